// Round 1
// baseline (9542.308 us; speedup 1.0000x reference)
//
#include <hip/hip_runtime.h>

// CADTopoEncoder: hetero-GNN (point/edge/face) with 2 SAGE layers + LN + pool.
// All f32. Strategy:
//   mean@Wl == segment_sum(src@Wl)/c  -> dense GEMM per relation, then scaled
//   atomic scatter directly into per-type accumulator.
//   x_dst@Wr + bl summed over relations -> folded into fused residual+ReLU+LN kernel.

#define POOL_SPLIT 16

__device__ __forceinline__ float wave_sum(float v) {
#pragma unroll
  for (int off = 32; off > 0; off >>= 1) v += __shfl_xor(v, off, 64);
  return v;
}

// ---------------- fused 2-layer MLP: h = relu(x@w1+b1)@w2 + b2 ----------------
template <int FIN>
__global__ __launch_bounds__(256) void mlp_kernel(
    const float* __restrict__ x, const float* __restrict__ w1,
    const float* __restrict__ b1, const float* __restrict__ w2,
    const float* __restrict__ b2, float* __restrict__ h, int n) {
  const int lane = threadIdx.x & 63;
  int wid = (blockIdx.x * blockDim.x + threadIdx.x) >> 6;
  const int nw = (gridDim.x * blockDim.x) >> 6;
  float w1c[FIN];
#pragma unroll
  for (int k = 0; k < FIN; ++k) w1c[k] = w1[k * 64 + lane];
  float w2c[64];
#pragma unroll
  for (int k = 0; k < 64; ++k) w2c[k] = w2[k * 64 + lane];
  const float b1v = b1[lane], b2v = b2[lane];
  for (int r = wid; r < n; r += nw) {
    float h1 = b1v;
#pragma unroll
    for (int k = 0; k < FIN; ++k) h1 = fmaf(x[(size_t)r * FIN + k], w1c[k], h1);
    h1 = fmaxf(h1, 0.f);
    float acc = b2v;
#pragma unroll
    for (int k = 0; k < 64; ++k) acc = fmaf(__shfl(h1, k, 64), w2c[k], acc);
    h[(size_t)r * 64 + lane] = acc;
  }
}

// ---------------- C[r][j] = sum_k A[r][k] * W[k][j] ----------------
// wave per row; W column j lives in 64 VGPRs of lane j; row broadcast via shfl.
__global__ __launch_bounds__(256) void gemm64_kernel(
    const float* __restrict__ A, const float* __restrict__ W,
    float* __restrict__ C, int n) {
  const int lane = threadIdx.x & 63;
  int wid = (blockIdx.x * blockDim.x + threadIdx.x) >> 6;
  const int nw = (gridDim.x * blockDim.x) >> 6;
  float wc[64];
#pragma unroll
  for (int k = 0; k < 64; ++k) wc[k] = W[k * 64 + lane];
  for (int r = wid; r < n; r += nw) {
    float a = A[(size_t)r * 64 + lane];
    float acc = 0.f;
#pragma unroll
    for (int k = 0; k < 64; ++k) acc = fmaf(__shfl(a, k, 64), wc[k], acc);
    C[(size_t)r * 64 + lane] = acc;
  }
}

// ---------------- per-relation dst-degree count ----------------
__global__ __launch_bounds__(256) void count_kernel(const int* __restrict__ dst,
                                                    float* __restrict__ c, int E) {
  int i = blockIdx.x * blockDim.x + threadIdx.x;
  if (i < E) unsafeAtomicAdd(c + dst[i], 1.f);
}

__global__ __launch_bounds__(256) void invc_kernel(float* __restrict__ c, int n) {
  int i = blockIdx.x * blockDim.x + threadIdx.x;
  if (i < n) c[i] = 1.f / fmaxf(c[i], 1.f);
}

// ---------------- scatter: o[dst] += g[src] * inv_c[dst] ----------------
// 16 lanes per edge, float4 gather, 4 atomics per lane.
__global__ __launch_bounds__(256) void scatter_kernel(
    const float* __restrict__ g, const int* __restrict__ ei,
    const float* __restrict__ invc, float* __restrict__ o, int E) {
  int idx = blockIdx.x * blockDim.x + threadIdx.x;
  if (idx >= E * 16) return;
  int e = idx >> 4, p = idx & 15;
  int s = ei[e];
  int d = ei[E + e];
  float ic = invc[d];
  float4 gv = *reinterpret_cast<const float4*>(g + (size_t)s * 64 + p * 4);
  float* ob = o + (size_t)d * 64 + p * 4;
  unsafeAtomicAdd(ob + 0, gv.x * ic);
  unsafeAtomicAdd(ob + 1, gv.y * ic);
  unsafeAtomicAdd(ob + 2, gv.z * ic);
  unsafeAtomicAdd(ob + 3, gv.w * ic);
}

// ---------------- precompute summed Wr / bl per (layer, dst-type) ----------------
// combo c = i*3 + t, t: 0=point(r 0..2), 1=edge(r 6..7), 2=face(r 3..5)
__global__ __launch_bounds__(256) void sumw_kernel(
    const float* __restrict__ Wr, const float* __restrict__ bl,
    float* __restrict__ wrs, float* __restrict__ bls) {
  int idx = blockIdx.x * blockDim.x + threadIdx.x;
  if (idx < 6 * 4096) {
    int c = idx >> 12, e = idx & 4095;
    int i = c / 3, t = c % 3;
    int rb = (t == 0) ? 0 : ((t == 1) ? 6 : 3);
    int rc = (t == 1) ? 2 : 3;
    float s = 0.f;
    for (int r = 0; r < rc; ++r) s += Wr[((size_t)(i * 8 + rb + r)) * 4096 + e];
    wrs[(size_t)c * 4096 + e] = s;
  } else if (idx < 6 * 4096 + 6 * 64) {
    int j = idx - 6 * 4096;
    int c = j >> 6, e = j & 63;
    int i = c / 3, t = c % 3;
    int rb = (t == 0) ? 0 : ((t == 1) ? 6 : 3);
    int rc = (t == 1) ? 2 : 3;
    float s = 0.f;
    for (int r = 0; r < rc; ++r) s += bl[(i * 8 + rb + r) * 64 + e];
    bls[c * 64 + e] = s;
  }
}

// ---------------- fused: h = LN(h + relu(o + h@Wrs + bls)) ----------------
__global__ __launch_bounds__(256) void final_kernel(
    float* __restrict__ h, const float* __restrict__ o,
    const float* __restrict__ wr, const float* __restrict__ bsum,
    const float* __restrict__ lng, const float* __restrict__ lnb, int n) {
  const int lane = threadIdx.x & 63;
  int wid = (blockIdx.x * blockDim.x + threadIdx.x) >> 6;
  const int nw = (gridDim.x * blockDim.x) >> 6;
  float wc[64];
#pragma unroll
  for (int k = 0; k < 64; ++k) wc[k] = wr[k * 64 + lane];
  const float bs = bsum[lane], gg = lng[lane], bb = lnb[lane];
  for (int r = wid; r < n; r += nw) {
    float hv = h[(size_t)r * 64 + lane];
    float acc = o[(size_t)r * 64 + lane] + bs;
#pragma unroll
    for (int k = 0; k < 64; ++k) acc = fmaf(__shfl(hv, k, 64), wc[k], acc);
    float v = hv + fmaxf(acc, 0.f);
    float m = wave_sum(v) * (1.f / 64.f);
    float d = v - m;
    float var = wave_sum(d * d) * (1.f / 64.f);
    float y = d * rsqrtf(var + 1e-5f) * gg + bb;
    h[(size_t)r * 64 + lane] = y;
  }
}

// ---------------- pool: per-(graph,split) partial sums over sorted batch ----------------
__global__ __launch_bounds__(64) void pool_kernel(
    const float* __restrict__ h, const int* __restrict__ batch,
    float* __restrict__ out, int n, int col_base) {
  const int lane = threadIdx.x;
  int gph = blockIdx.x >> 4;  // POOL_SPLIT = 16
  int s = blockIdx.x & 15;
  int lo = 0, hi = n;
  while (lo < hi) { int mid = (lo + hi) >> 1; if (batch[mid] < gph) lo = mid + 1; else hi = mid; }
  int beg = lo;
  hi = n;
  while (lo < hi) { int mid = (lo + hi) >> 1; if (batch[mid] < gph + 1) lo = mid + 1; else hi = mid; }
  int end = lo;
  int cnt = end - beg;
  if (cnt <= 0) return;
  int per = (cnt + POOL_SPLIT - 1) >> 4;
  int rb = beg + s * per;
  int re = min(rb + per, end);
  if (rb >= re) return;
  float acc = 0.f;
  for (int r = rb; r < re; ++r) acc += h[(size_t)r * 64 + lane];
  unsafeAtomicAdd(out + gph * 192 + col_base + lane, acc);
}

__global__ __launch_bounds__(256) void pool_scale_kernel(
    float* __restrict__ out, const int* __restrict__ bp,
    const int* __restrict__ be, const int* __restrict__ bf,
    int np, int ne, int nf) {
  int idx = blockIdx.x * blockDim.x + threadIdx.x;
  if (idx >= 64 * 192) return;
  int gph = idx / 192, col = idx % 192;
  const int* b;
  int n;
  if (col < 64) { b = bp; n = np; }
  else if (col < 128) { b = be; n = ne; }
  else { b = bf; n = nf; }
  int lo = 0, hi = n;
  while (lo < hi) { int mid = (lo + hi) >> 1; if (b[mid] < gph) lo = mid + 1; else hi = mid; }
  int beg = lo;
  hi = n;
  while (lo < hi) { int mid = (lo + hi) >> 1; if (b[mid] < gph + 1) lo = mid + 1; else hi = mid; }
  int cnt = lo - beg;
  out[idx] = out[idx] / fmaxf((float)cnt, 1.f);
}

extern "C" void kernel_launch(void* const* d_in, const int* in_sizes, int n_in,
                              void* d_out, int out_size, void* d_ws, size_t ws_size,
                              hipStream_t stream) {
  const float* point_x = (const float*)d_in[0];
  const float* edge_x  = (const float*)d_in[1];
  const float* face_x  = (const float*)d_in[2];
  const int* bp = (const int*)d_in[3];
  const int* be = (const int*)d_in[4];
  const int* bf = (const int*)d_in[5];
  const int NP = in_sizes[3], NE = in_sizes[4], NF = in_sizes[5];
  const int Eg = in_sizes[6] / 2;

  const float* Wl  = (const float*)d_in[26];
  const float* blp = (const float*)d_in[27];
  const float* Wr  = (const float*)d_in[28];
  const float* lng = (const float*)d_in[29];
  const float* lnb = (const float*)d_in[30];

  // ---- workspace layout (floats) ----
  float* ws = (float*)d_ws;
  size_t off = 0;
  float* hp = ws + off; off += (size_t)NP * 64;
  float* he = ws + off; off += (size_t)NE * 64;
  float* hf = ws + off; off += (size_t)NF * 64;
  float* op  = ws + off; off += (size_t)NP * 64;
  float* oe  = ws + off; off += (size_t)NE * 64;
  float* of_ = ws + off; off += (size_t)NF * 64;
  float* g = ws + off; off += (size_t)NP * 64;  // max src rows = NP
  float* cnt = ws + off;
  size_t cnt_sz = 3 * (size_t)NP + 3 * (size_t)NF + 2 * (size_t)NE;
  off += cnt_sz;
  float* wrs = ws + off; off += 6 * 4096;
  float* bls = ws + off; off += 6 * 64;
  // total ~234 MB

  // relation tables: order pp, fp, ep, pf, ef, ff, pe, fe
  const int* ei[8] = {(const int*)d_in[6],  (const int*)d_in[7],
                      (const int*)d_in[8],  (const int*)d_in[9],
                      (const int*)d_in[10], (const int*)d_in[11],
                      (const int*)d_in[12], (const int*)d_in[13]};
  const float* hsrc[8] = {hp, hf, he, hp, he, hf, hp, hf};
  int nsrc[8] = {NP, NF, NE, NP, NE, NF, NP, NF};
  float* odst[8] = {op, op, op, of_, of_, of_, oe, oe};
  float* invc[8];
  invc[0] = cnt;
  invc[1] = cnt + (size_t)NP;
  invc[2] = cnt + 2 * (size_t)NP;
  invc[3] = cnt + 3 * (size_t)NP;
  invc[4] = invc[3] + (size_t)NF;
  invc[5] = invc[3] + 2 * (size_t)NF;
  invc[6] = invc[3] + 3 * (size_t)NF;
  invc[7] = invc[6] + (size_t)NE;

  // ---- degree counts (per call; edge indices are inputs) ----
  hipMemsetAsync(cnt, 0, cnt_sz * sizeof(float), stream);
  int cblk = (Eg + 255) / 256;
  for (int r = 0; r < 8; ++r)
    count_kernel<<<cblk, 256, 0, stream>>>(ei[r] + Eg, invc[r], Eg);
  invc_kernel<<<(int)((cnt_sz + 255) / 256), 256, 0, stream>>>(cnt, (int)cnt_sz);

  // ---- summed Wr / bl per (layer, type) ----
  sumw_kernel<<<(6 * 4096 + 6 * 64 + 255) / 256, 256, 0, stream>>>(Wr, blp, wrs, bls);

  // ---- input MLPs ----
  mlp_kernel<3><<<1024, 256, 0, stream>>>(point_x, (const float*)d_in[14],
      (const float*)d_in[15], (const float*)d_in[16], (const float*)d_in[17], hp, NP);
  mlp_kernel<2><<<1024, 256, 0, stream>>>(edge_x, (const float*)d_in[18],
      (const float*)d_in[19], (const float*)d_in[20], (const float*)d_in[21], he, NE);
  mlp_kernel<16><<<1024, 256, 0, stream>>>(face_x, (const float*)d_in[22],
      (const float*)d_in[23], (const float*)d_in[24], (const float*)d_in[25], hf, NF);

  // ---- 2 hetero-SAGE layers ----
  const int swork = Eg * 16;
  const int sblk = (swork + 255) / 256;
  for (int i = 0; i < 2; ++i) {
    hipMemsetAsync(op, 0, ((size_t)NP + NE + NF) * 64 * sizeof(float), stream);
    for (int r = 0; r < 8; ++r) {
      gemm64_kernel<<<1024, 256, 0, stream>>>(
          hsrc[r], Wl + ((size_t)(i * 8 + r)) * 4096, g, nsrc[r]);
      scatter_kernel<<<sblk, 256, 0, stream>>>(g, ei[r], invc[r], odst[r], Eg);
    }
    final_kernel<<<1024, 256, 0, stream>>>(hp, op, wrs + (size_t)(i * 3 + 0) * 4096,
        bls + (i * 3 + 0) * 64, lng + (i * 3 + 0) * 64, lnb + (i * 3 + 0) * 64, NP);
    final_kernel<<<1024, 256, 0, stream>>>(he, oe, wrs + (size_t)(i * 3 + 1) * 4096,
        bls + (i * 3 + 1) * 64, lng + (i * 3 + 1) * 64, lnb + (i * 3 + 1) * 64, NE);
    final_kernel<<<1024, 256, 0, stream>>>(hf, of_, wrs + (size_t)(i * 3 + 2) * 4096,
        bls + (i * 3 + 2) * 64, lng + (i * 3 + 2) * 64, lnb + (i * 3 + 2) * 64, NF);
  }

  // ---- pool + scale ----
  float* out = (float*)d_out;
  hipMemsetAsync(out, 0, (size_t)out_size * sizeof(float), stream);
  pool_kernel<<<64 * POOL_SPLIT, 64, 0, stream>>>(hp, bp, out, NP, 0);
  pool_kernel<<<64 * POOL_SPLIT, 64, 0, stream>>>(he, be, out, NE, 64);
  pool_kernel<<<64 * POOL_SPLIT, 64, 0, stream>>>(hf, bf, out, NF, 128);
  pool_scale_kernel<<<(64 * 192 + 255) / 256, 256, 0, stream>>>(out, bp, be, bf, NP, NE, NF);
}

// Round 2
// 3765.554 us; speedup vs baseline: 2.5341x; 2.5341x over previous
//
#include <hip/hip_runtime.h>
#include <hip/hip_bf16.h>

// CADTopoEncoder: hetero-GNN (point/edge/face), 2 SAGE layers + LN + pool. f32.
// mean@Wl == segment_sum(src@Wl)/deg -> dense GEMM (bf16 out) + CSR gather (no atomics).
// x_dst@Wr + bl summed per dst type -> folded into fused residual+ReLU+LN kernel.

#define POOL_SPLIT 16

__device__ __forceinline__ float wave_sum(float v) {
#pragma unroll
  for (int off = 32; off > 0; off >>= 1) v += __shfl_xor(v, off, 64);
  return v;
}

// ---------------- fused 2-layer MLP: h = relu(x@w1+b1)@w2 + b2 ----------------
template <int FIN>
__global__ __launch_bounds__(256) void mlp_kernel(
    const float* __restrict__ x, const float* __restrict__ w1,
    const float* __restrict__ b1, const float* __restrict__ w2,
    const float* __restrict__ b2, float* __restrict__ h, int n) {
  const int lane = threadIdx.x & 63;
  int wid = (blockIdx.x * blockDim.x + threadIdx.x) >> 6;
  const int nw = (gridDim.x * blockDim.x) >> 6;
  float w1c[FIN];
#pragma unroll
  for (int k = 0; k < FIN; ++k) w1c[k] = w1[k * 64 + lane];
  float w2c[64];
#pragma unroll
  for (int k = 0; k < 64; ++k) w2c[k] = w2[k * 64 + lane];
  const float b1v = b1[lane], b2v = b2[lane];
  for (int r = wid; r < n; r += nw) {
    float h1 = b1v;
#pragma unroll
    for (int k = 0; k < FIN; ++k) h1 = fmaf(x[(size_t)r * FIN + k], w1c[k], h1);
    h1 = fmaxf(h1, 0.f);
    float acc = b2v;
#pragma unroll
    for (int k = 0; k < 64; ++k) acc = fmaf(__shfl(h1, k, 64), w2c[k], acc);
    h[(size_t)r * 64 + lane] = acc;
  }
}

// ---------------- g[r][j] = sum_k A[r][k] * W[k][j], bf16 output ----------------
__global__ __launch_bounds__(256) void gemm64_bf16_kernel(
    const float* __restrict__ A, const float* __restrict__ W,
    __hip_bfloat16* __restrict__ C, int n) {
  const int lane = threadIdx.x & 63;
  int wid = (blockIdx.x * blockDim.x + threadIdx.x) >> 6;
  const int nw = (gridDim.x * blockDim.x) >> 6;
  float wc[64];
#pragma unroll
  for (int k = 0; k < 64; ++k) wc[k] = W[k * 64 + lane];
  for (int r = wid; r < n; r += nw) {
    float a = A[(size_t)r * 64 + lane];
    float acc = 0.f;
#pragma unroll
    for (int k = 0; k < 64; ++k) acc = fmaf(__shfl(a, k, 64), wc[k], acc);
    C[(size_t)r * 64 + lane] = __float2bfloat16(acc);
  }
}

// ---------------- CSR build: count, scan (3 kernels), fill ----------------
__global__ __launch_bounds__(256) void count_kernel(const int* __restrict__ dst,
                                                    int* __restrict__ c, int E) {
  int i = blockIdx.x * blockDim.x + threadIdx.x;
  if (i < E) atomicAdd(c + dst[i], 1);
}

__global__ __launch_bounds__(256) void scan1_kernel(const int* __restrict__ cnt,
                                                    int* __restrict__ part, int n) {
  __shared__ int wt[4];
  int base = blockIdx.x * 1024;
  int t = 0;
  for (int i = threadIdx.x; i < 1024; i += 256) {
    int idx = base + i;
    if (idx < n) t += cnt[idx];
  }
#pragma unroll
  for (int d = 32; d > 0; d >>= 1) t += __shfl_xor(t, d, 64);
  if ((threadIdx.x & 63) == 0) wt[threadIdx.x >> 6] = t;
  __syncthreads();
  if (threadIdx.x == 0) part[blockIdx.x] = wt[0] + wt[1] + wt[2] + wt[3];
}

__global__ __launch_bounds__(1024) void scan2_kernel(int* __restrict__ part,
                                                     int* __restrict__ off, int nb,
                                                     int n, int total) {
  __shared__ int lds[1024];
  int tid = threadIdx.x;
  int v = (tid < nb) ? part[tid] : 0;
  lds[tid] = v;
  __syncthreads();
  for (int d = 1; d < 1024; d <<= 1) {
    int y = (tid >= d) ? lds[tid - d] : 0;
    __syncthreads();
    lds[tid] += y;
    __syncthreads();
  }
  if (tid < nb) part[tid] = lds[tid] - v;  // exclusive
  if (tid == 0) off[n] = total;
}

__global__ __launch_bounds__(256) void scan3_kernel(const int* __restrict__ cnt,
                                                    const int* __restrict__ part,
                                                    int* __restrict__ off, int n) {
  __shared__ int wt[4];
  int base = blockIdx.x * 1024 + threadIdx.x * 4;
  int c[4];
#pragma unroll
  for (int k = 0; k < 4; ++k) {
    int idx = base + k;
    c[k] = (idx < n) ? cnt[idx] : 0;
  }
  int t = c[0] + c[1] + c[2] + c[3];
  int lane = threadIdx.x & 63, w = threadIdx.x >> 6;
  int x = t;
#pragma unroll
  for (int d = 1; d < 64; d <<= 1) {
    int y = __shfl_up(x, d, 64);
    if (lane >= d) x += y;
  }
  int ex = x - t;
  if (lane == 63) wt[w] = x;
  __syncthreads();
  int woff = 0;
#pragma unroll
  for (int k = 0; k < 4; ++k)
    if (k < w) woff += wt[k];
  int pos = part[blockIdx.x] + woff + ex;
#pragma unroll
  for (int k = 0; k < 4; ++k) {
    int idx = base + k;
    if (idx < n) off[idx] = pos;
    pos += c[k];
  }
}

__global__ __launch_bounds__(256) void fill_kernel(const int* __restrict__ ei,
                                                   const int* __restrict__ off,
                                                   int* __restrict__ cur,
                                                   int* __restrict__ srcs,
                                                   int base, int E) {
  int e = blockIdx.x * blockDim.x + threadIdx.x;
  if (e >= E) return;
  int s = ei[e], d = ei[E + e];
  int p = off[base + d] + atomicAdd(cur + base + d, 1);
  srcs[p] = s;
}

// ---------------- gather: o[d] (+)= mean_{j in CSR(d)} g[src_j] ----------------
__global__ __launch_bounds__(256) void gather_kernel(
    const __hip_bfloat16* __restrict__ g, const int* __restrict__ srcs,
    const int* __restrict__ off, int base, float* __restrict__ o, int ndst,
    int first) {
  const int lane = threadIdx.x & 63;
  int wid = (blockIdx.x * blockDim.x + threadIdx.x) >> 6;
  const int nw = (gridDim.x * blockDim.x) >> 6;
  int rpw = (ndst + nw - 1) / nw;
  int r0 = wid * rpw;
  int r1 = min(r0 + rpw, ndst);
  for (int d = r0; d < r1; ++d) {
    int b0 = off[base + d], b1 = off[base + d + 1];
    float acc = 0.f;
    for (int j = b0; j < b1; ++j) {
      int s = srcs[j];
      acc += __bfloat162float(g[(size_t)s * 64 + lane]);
    }
    float v = acc / fmaxf((float)(b1 - b0), 1.f);
    if (first)
      o[(size_t)d * 64 + lane] = v;
    else
      o[(size_t)d * 64 + lane] += v;
  }
}

// ---------------- precompute summed Wr / bl per (layer, dst-type) ----------------
__global__ __launch_bounds__(256) void sumw_kernel(
    const float* __restrict__ Wr, const float* __restrict__ bl,
    float* __restrict__ wrs, float* __restrict__ bls) {
  int idx = blockIdx.x * blockDim.x + threadIdx.x;
  if (idx < 6 * 4096) {
    int c = idx >> 12, e = idx & 4095;
    int i = c / 3, t = c % 3;
    int rb = (t == 0) ? 0 : ((t == 1) ? 6 : 3);
    int rc = (t == 1) ? 2 : 3;
    float s = 0.f;
    for (int r = 0; r < rc; ++r) s += Wr[((size_t)(i * 8 + rb + r)) * 4096 + e];
    wrs[(size_t)c * 4096 + e] = s;
  } else if (idx < 6 * 4096 + 6 * 64) {
    int j = idx - 6 * 4096;
    int c = j >> 6, e = j & 63;
    int i = c / 3, t = c % 3;
    int rb = (t == 0) ? 0 : ((t == 1) ? 6 : 3);
    int rc = (t == 1) ? 2 : 3;
    float s = 0.f;
    for (int r = 0; r < rc; ++r) s += bl[(i * 8 + rb + r) * 64 + e];
    bls[c * 64 + e] = s;
  }
}

// ---------------- fused: h = LN(h + relu(o + h@Wrs + bls)) ----------------
__global__ __launch_bounds__(256) void final_kernel(
    float* __restrict__ h, const float* __restrict__ o,
    const float* __restrict__ wr, const float* __restrict__ bsum,
    const float* __restrict__ lng, const float* __restrict__ lnb, int n) {
  const int lane = threadIdx.x & 63;
  int wid = (blockIdx.x * blockDim.x + threadIdx.x) >> 6;
  const int nw = (gridDim.x * blockDim.x) >> 6;
  float wc[64];
#pragma unroll
  for (int k = 0; k < 64; ++k) wc[k] = wr[k * 64 + lane];
  const float bs = bsum[lane], gg = lng[lane], bb = lnb[lane];
  for (int r = wid; r < n; r += nw) {
    float hv = h[(size_t)r * 64 + lane];
    float acc = o[(size_t)r * 64 + lane] + bs;
#pragma unroll
    for (int k = 0; k < 64; ++k) acc = fmaf(__shfl(hv, k, 64), wc[k], acc);
    float v = hv + fmaxf(acc, 0.f);
    float m = wave_sum(v) * (1.f / 64.f);
    float d = v - m;
    float var = wave_sum(d * d) * (1.f / 64.f);
    float y = d * rsqrtf(var + 1e-5f) * gg + bb;
    h[(size_t)r * 64 + lane] = y;
  }
}

// ---------------- pool: per-(graph,split) partial sums over sorted batch ----------------
__global__ __launch_bounds__(64) void pool_kernel(
    const float* __restrict__ h, const int* __restrict__ batch,
    float* __restrict__ out, int n, int col_base) {
  const int lane = threadIdx.x;
  int gph = blockIdx.x >> 4;  // POOL_SPLIT = 16
  int s = blockIdx.x & 15;
  int lo = 0, hi = n;
  while (lo < hi) { int mid = (lo + hi) >> 1; if (batch[mid] < gph) lo = mid + 1; else hi = mid; }
  int beg = lo;
  hi = n;
  while (lo < hi) { int mid = (lo + hi) >> 1; if (batch[mid] < gph + 1) lo = mid + 1; else hi = mid; }
  int end = lo;
  int cnt = end - beg;
  if (cnt <= 0) return;
  int per = (cnt + POOL_SPLIT - 1) >> 4;
  int rb = beg + s * per;
  int re = min(rb + per, end);
  if (rb >= re) return;
  float acc = 0.f;
  for (int r = rb; r < re; ++r) acc += h[(size_t)r * 64 + lane];
  unsafeAtomicAdd(out + gph * 192 + col_base + lane, acc);
}

__global__ __launch_bounds__(256) void pool_scale_kernel(
    float* __restrict__ out, const int* __restrict__ bp,
    const int* __restrict__ be, const int* __restrict__ bf,
    int np, int ne, int nf) {
  int idx = blockIdx.x * blockDim.x + threadIdx.x;
  if (idx >= 64 * 192) return;
  int gph = idx / 192, col = idx % 192;
  const int* b;
  int n;
  if (col < 64) { b = bp; n = np; }
  else if (col < 128) { b = be; n = ne; }
  else { b = bf; n = nf; }
  int lo = 0, hi = n;
  while (lo < hi) { int mid = (lo + hi) >> 1; if (b[mid] < gph) lo = mid + 1; else hi = mid; }
  int beg = lo;
  hi = n;
  while (lo < hi) { int mid = (lo + hi) >> 1; if (b[mid] < gph + 1) lo = mid + 1; else hi = mid; }
  int cnt = lo - beg;
  out[idx] = out[idx] / fmaxf((float)cnt, 1.f);
}

extern "C" void kernel_launch(void* const* d_in, const int* in_sizes, int n_in,
                              void* d_out, int out_size, void* d_ws, size_t ws_size,
                              hipStream_t stream) {
  const float* point_x = (const float*)d_in[0];
  const float* edge_x  = (const float*)d_in[1];
  const float* face_x  = (const float*)d_in[2];
  const int* bp = (const int*)d_in[3];
  const int* be = (const int*)d_in[4];
  const int* bf = (const int*)d_in[5];
  const int NP = in_sizes[3], NE = in_sizes[4], NF = in_sizes[5];
  const int Eg = in_sizes[6] / 2;

  const float* Wl  = (const float*)d_in[26];
  const float* blp = (const float*)d_in[27];
  const float* Wr  = (const float*)d_in[28];
  const float* lng = (const float*)d_in[29];
  const float* lnb = (const float*)d_in[30];

  // ---- workspace layout (bytes) ----
  char* p = (char*)d_ws;
  float* hp = (float*)p; p += (size_t)NP * 64 * 4;
  float* he = (float*)p; p += (size_t)NE * 64 * 4;
  float* hf = (float*)p; p += (size_t)NF * 64 * 4;
  float* op  = (float*)p; p += (size_t)NP * 64 * 4;
  float* oe  = (float*)p; p += (size_t)NE * 64 * 4;
  float* of_ = (float*)p; p += (size_t)NF * 64 * 4;
  __hip_bfloat16* g = (__hip_bfloat16*)p; p += (size_t)NP * 64 * 2;  // max src rows
  int* srcs = (int*)p; p += (size_t)8 * Eg * 4;
  const int NDSUM = 3 * NP + 3 * NF + 2 * NE;
  int* off = (int*)p; p += (size_t)(NDSUM + 1) * 4;
  int* cur = (int*)p; p += (size_t)NDSUM * 4;
  int* part = (int*)p; p += 1024 * 4;
  float* wrs = (float*)p; p += 6 * 4096 * 4;
  float* bls = (float*)p; p += 6 * 64 * 4;
  // total ~228.5 MB

  // relation tables: order pp, fp, ep, pf, ef, ff, pe, fe
  const int* ei[8] = {(const int*)d_in[6],  (const int*)d_in[7],
                      (const int*)d_in[8],  (const int*)d_in[9],
                      (const int*)d_in[10], (const int*)d_in[11],
                      (const int*)d_in[12], (const int*)d_in[13]};
  const float* hsrc[8] = {hp, hf, he, hp, he, hf, hp, hf};
  int nsrc[8] = {NP, NF, NE, NP, NE, NF, NP, NF};
  int ndst[8] = {NP, NP, NP, NF, NF, NF, NE, NE};
  float* odst[8] = {op, op, op, of_, of_, of_, oe, oe};
  int first[8] = {1, 0, 0, 1, 0, 0, 1, 0};
  int base[8];
  base[0] = 0;
  for (int r = 1; r < 8; ++r) base[r] = base[r - 1] + ndst[r - 1];

  // ---- CSR build (edges identical across layers -> once per call) ----
  const int cblk = (Eg + 255) / 256;
  hipMemsetAsync(cur, 0, (size_t)NDSUM * 4, stream);
  for (int r = 0; r < 8; ++r)
    count_kernel<<<cblk, 256, 0, stream>>>(ei[r] + Eg, cur + base[r], Eg);
  const int nb = (NDSUM + 1023) / 1024;
  scan1_kernel<<<nb, 256, 0, stream>>>(cur, part, NDSUM);
  scan2_kernel<<<1, 1024, 0, stream>>>(part, off, nb, NDSUM, 8 * Eg);
  scan3_kernel<<<nb, 256, 0, stream>>>(cur, part, off, NDSUM);
  hipMemsetAsync(cur, 0, (size_t)NDSUM * 4, stream);
  for (int r = 0; r < 8; ++r)
    fill_kernel<<<cblk, 256, 0, stream>>>(ei[r], off, cur, srcs, base[r], Eg);

  // ---- summed Wr / bl per (layer, type) ----
  sumw_kernel<<<(6 * 4096 + 6 * 64 + 255) / 256, 256, 0, stream>>>(Wr, blp, wrs, bls);

  // ---- input MLPs ----
  mlp_kernel<3><<<1024, 256, 0, stream>>>(point_x, (const float*)d_in[14],
      (const float*)d_in[15], (const float*)d_in[16], (const float*)d_in[17], hp, NP);
  mlp_kernel<2><<<1024, 256, 0, stream>>>(edge_x, (const float*)d_in[18],
      (const float*)d_in[19], (const float*)d_in[20], (const float*)d_in[21], he, NE);
  mlp_kernel<16><<<1024, 256, 0, stream>>>(face_x, (const float*)d_in[22],
      (const float*)d_in[23], (const float*)d_in[24], (const float*)d_in[25], hf, NF);

  // ---- 2 hetero-SAGE layers ----
  for (int i = 0; i < 2; ++i) {
    // all g-GEMMs read pre-update h; finals run only after every gather
    for (int r = 0; r < 8; ++r) {
      gemm64_bf16_kernel<<<1024, 256, 0, stream>>>(
          hsrc[r], Wl + ((size_t)(i * 8 + r)) * 4096, g, nsrc[r]);
      gather_kernel<<<2048, 256, 0, stream>>>(g, srcs, off, base[r], odst[r],
                                              ndst[r], first[r]);
    }
    final_kernel<<<1024, 256, 0, stream>>>(hp, op, wrs + (size_t)(i * 3 + 0) * 4096,
        bls + (i * 3 + 0) * 64, lng + (i * 3 + 0) * 64, lnb + (i * 3 + 0) * 64, NP);
    final_kernel<<<1024, 256, 0, stream>>>(he, oe, wrs + (size_t)(i * 3 + 1) * 4096,
        bls + (i * 3 + 1) * 64, lng + (i * 3 + 1) * 64, lnb + (i * 3 + 1) * 64, NE);
    final_kernel<<<1024, 256, 0, stream>>>(hf, of_, wrs + (size_t)(i * 3 + 2) * 4096,
        bls + (i * 3 + 2) * 64, lng + (i * 3 + 2) * 64, lnb + (i * 3 + 2) * 64, NF);
  }

  // ---- pool + scale ----
  float* out = (float*)d_out;
  hipMemsetAsync(out, 0, (size_t)out_size * sizeof(float), stream);
  pool_kernel<<<64 * POOL_SPLIT, 64, 0, stream>>>(hp, bp, out, NP, 0);
  pool_kernel<<<64 * POOL_SPLIT, 64, 0, stream>>>(he, be, out, NE, 64);
  pool_kernel<<<64 * POOL_SPLIT, 64, 0, stream>>>(hf, bf, out, NF, 128);
  pool_scale_kernel<<<(64 * 192 + 255) / 256, 256, 0, stream>>>(out, bp, be, bf, NP, NE, NF);
}

// Round 3
// 1598.786 us; speedup vs baseline: 5.9685x; 2.3553x over previous
//
#include <hip/hip_runtime.h>
#include <hip/hip_bf16.h>

// CADTopoEncoder: hetero-GNN (point/edge/face), 2 SAGE layers + LN + pool.
// All hidden state in bf16 (double-buffered). All (n,64)@(64,64) matmuls via
// mfma_f32_16x16x32_bf16 with fragment-preordered weights. Per-dst-type fused
// kernel: CSR gather of all relations + t(=h@Wrs) + bl + relu + residual + LN.

#define POOL_SPLIT 16

typedef __attribute__((ext_vector_type(8))) short bf8_t;   // 8 bf16 in 4 VGPRs
typedef __attribute__((ext_vector_type(4))) float f32x4;

__device__ __forceinline__ ushort f2bf(float f) {
  union { __hip_bfloat16 b; ushort u; } v;
  v.b = __float2bfloat16(f);
  return v.u;
}
__device__ __forceinline__ float u2f(ushort u) {
  union { ushort u; __hip_bfloat16 b; } v;
  v.u = u;
  return __bfloat162float(v.b);
}

__device__ __forceinline__ float wave_sum(float v) {
#pragma unroll
  for (int off = 32; off > 0; off >>= 1) v += __shfl_xor(v, off, 64);
  return v;
}

// ---------------- prep: weights -> bf16 MFMA fragment order, summed biases ----
// fw holds 25 matrices (4096 bf16 each):
//   m 0..15 : Wl[i*8+rel]
//   m 16..21: Wrs summed per (layer i, type t) , t: 0=point 1=edge 2=face
//   m 22..24: mlp w2 for p/e/f
// fragment element e = ((ct*2+ks)*64 + lane)*8 + b  <- W[ks*32+(lane>>4)*8+b][ct*16+(lane&15)]
__global__ __launch_bounds__(256) void prep_kernel(
    const float* __restrict__ Wl, const float* __restrict__ Wr,
    const float* __restrict__ bl, const float* __restrict__ w2p,
    const float* __restrict__ w2e, const float* __restrict__ w2f,
    ushort* __restrict__ fw, float* __restrict__ bls) {
  int idx = blockIdx.x * blockDim.x + threadIdx.x;
  if (idx < 25 * 4096) {
    int m = idx >> 12, e = idx & 4095;
    int i8 = e >> 3, b = e & 7;
    int lane = i8 & 63, cb = i8 >> 6;
    int ks = cb & 1, ct = cb >> 1;
    int k = ks * 32 + ((lane >> 4) << 3) + b;
    int col = (ct << 4) + (lane & 15);
    int widx = (k << 6) + col;
    float v;
    if (m < 16) {
      v = Wl[(size_t)m * 4096 + widx];
    } else if (m < 22) {
      int c = m - 16, i = c / 3, t = c % 3;
      int rb = (t == 0) ? 0 : ((t == 1) ? 6 : 3);
      int rc = (t == 1) ? 2 : 3;
      v = 0.f;
      for (int r = 0; r < rc; ++r) v += Wr[(size_t)(i * 8 + rb + r) * 4096 + widx];
    } else {
      const float* w2 = (m == 22) ? w2p : ((m == 23) ? w2e : w2f);
      v = w2[widx];
    }
    fw[idx] = f2bf(v);
  } else if (idx < 25 * 4096 + 6 * 64) {
    int j = idx - 25 * 4096;
    int c = j >> 6, e = j & 63;
    int i = c / 3, t = c % 3;
    int rb = (t == 0) ? 0 : ((t == 1) ? 6 : 3);
    int rc = (t == 1) ? 2 : 3;
    float s = 0.f;
    for (int r = 0; r < rc; ++r) s += bl[(i * 8 + rb + r) * 64 + e];
    bls[c * 64 + e] = s;
  }
}

// ---------------- MFMA GEMM: C[n,64](bf16) = A[n,64](bf16) @ W (+bias) -------
// wave = 32 rows: 2 row-tiles x 4 col-tiles x 2 k-steps = 16 MFMAs.
__global__ __launch_bounds__(256) void gemm_mfma_kernel(
    const ushort* __restrict__ A, const ushort* __restrict__ fw,
    const float* __restrict__ bias, ushort* __restrict__ C, int n) {
  const int lane = threadIdx.x & 63;
  const int wid = (blockIdx.x * blockDim.x + threadIdx.x) >> 6;
  const int r0 = wid * 32;
  if (r0 >= n) return;
  bf8_t bw[8];
#pragma unroll
  for (int i = 0; i < 8; ++i)
    bw[i] = *(const bf8_t*)(fw + ((i << 6) + lane) * 8);
  const int koff = ((lane >> 4) << 3);
  int ra = r0 + (lane & 15);
  int rb = ra + 16;
  ra = min(ra, n - 1);
  rb = min(rb, n - 1);
  const bf8_t a00 = *(const bf8_t*)(A + (size_t)ra * 64 + koff);
  const bf8_t a01 = *(const bf8_t*)(A + (size_t)ra * 64 + 32 + koff);
  const bf8_t a10 = *(const bf8_t*)(A + (size_t)rb * 64 + koff);
  const bf8_t a11 = *(const bf8_t*)(A + (size_t)rb * 64 + 32 + koff);
  f32x4 acc[8];
#pragma unroll
  for (int i = 0; i < 8; ++i) acc[i] = (f32x4){0.f, 0.f, 0.f, 0.f};
#pragma unroll
  for (int ct = 0; ct < 4; ++ct) {
    acc[ct]     = __builtin_amdgcn_mfma_f32_16x16x32_bf16(a00, bw[ct * 2 + 0], acc[ct], 0, 0, 0);
    acc[ct]     = __builtin_amdgcn_mfma_f32_16x16x32_bf16(a01, bw[ct * 2 + 1], acc[ct], 0, 0, 0);
    acc[4 + ct] = __builtin_amdgcn_mfma_f32_16x16x32_bf16(a10, bw[ct * 2 + 0], acc[4 + ct], 0, 0, 0);
    acc[4 + ct] = __builtin_amdgcn_mfma_f32_16x16x32_bf16(a11, bw[ct * 2 + 1], acc[4 + ct], 0, 0, 0);
  }
  float bv[4] = {0.f, 0.f, 0.f, 0.f};
  if (bias) {
#pragma unroll
    for (int ct = 0; ct < 4; ++ct) bv[ct] = bias[ct * 16 + (lane & 15)];
  }
  const int rowb = r0 + ((lane >> 4) << 2);
  const int cb = lane & 15;
#pragma unroll
  for (int rt = 0; rt < 2; ++rt) {
#pragma unroll
    for (int q = 0; q < 4; ++q) {
      int row = rowb + rt * 16 + q;
      if (row < n) {
#pragma unroll
        for (int ct = 0; ct < 4; ++ct)
          C[(size_t)row * 64 + ct * 16 + cb] = f2bf(acc[rt * 4 + ct][q] + bv[ct]);
      }
    }
  }
}

// ---------------- mlp stage 1: h1 = relu(x@w1+b1) -> bf16 --------------------
template <int FIN>
__global__ __launch_bounds__(256) void mlp1_kernel(
    const float* __restrict__ x, const float* __restrict__ w1,
    const float* __restrict__ b1, ushort* __restrict__ h1, int n) {
  const int lane = threadIdx.x & 63;
  int wid = (blockIdx.x * blockDim.x + threadIdx.x) >> 6;
  const int nw = (gridDim.x * blockDim.x) >> 6;
  float w1c[FIN];
#pragma unroll
  for (int k = 0; k < FIN; ++k) w1c[k] = w1[k * 64 + lane];
  const float b1v = b1[lane];
  for (int r = wid; r < n; r += nw) {
    float s = b1v;
#pragma unroll
    for (int k = 0; k < FIN; ++k) s = fmaf(x[(size_t)r * FIN + k], w1c[k], s);
    h1[(size_t)r * 64 + lane] = f2bf(fmaxf(s, 0.f));
  }
}

// ---------------- CSR build: count, scan (3 kernels), fill -------------------
__global__ __launch_bounds__(256) void count_kernel(const int* __restrict__ dst,
                                                    int* __restrict__ c, int E) {
  int i = blockIdx.x * blockDim.x + threadIdx.x;
  if (i < E) atomicAdd(c + dst[i], 1);
}

__global__ __launch_bounds__(256) void scan1_kernel(const int* __restrict__ cnt,
                                                    int* __restrict__ part, int n) {
  __shared__ int wt[4];
  int base = blockIdx.x * 1024;
  int t = 0;
  for (int i = threadIdx.x; i < 1024; i += 256) {
    int idx = base + i;
    if (idx < n) t += cnt[idx];
  }
#pragma unroll
  for (int d = 32; d > 0; d >>= 1) t += __shfl_xor(t, d, 64);
  if ((threadIdx.x & 63) == 0) wt[threadIdx.x >> 6] = t;
  __syncthreads();
  if (threadIdx.x == 0) part[blockIdx.x] = wt[0] + wt[1] + wt[2] + wt[3];
}

__global__ __launch_bounds__(1024) void scan2_kernel(int* __restrict__ part,
                                                     int* __restrict__ off, int nb,
                                                     int n, int total) {
  __shared__ int lds[1024];
  int tid = threadIdx.x;
  int v = (tid < nb) ? part[tid] : 0;
  lds[tid] = v;
  __syncthreads();
  for (int d = 1; d < 1024; d <<= 1) {
    int y = (tid >= d) ? lds[tid - d] : 0;
    __syncthreads();
    lds[tid] += y;
    __syncthreads();
  }
  if (tid < nb) part[tid] = lds[tid] - v;  // exclusive
  if (tid == 0) off[n] = total;
}

__global__ __launch_bounds__(256) void scan3_kernel(const int* __restrict__ cnt,
                                                    const int* __restrict__ part,
                                                    int* __restrict__ off, int n) {
  __shared__ int wt[4];
  int base = blockIdx.x * 1024 + threadIdx.x * 4;
  int c[4];
#pragma unroll
  for (int k = 0; k < 4; ++k) {
    int idx = base + k;
    c[k] = (idx < n) ? cnt[idx] : 0;
  }
  int t = c[0] + c[1] + c[2] + c[3];
  int lane = threadIdx.x & 63, w = threadIdx.x >> 6;
  int x = t;
#pragma unroll
  for (int d = 1; d < 64; d <<= 1) {
    int y = __shfl_up(x, d, 64);
    if (lane >= d) x += y;
  }
  int ex = x - t;
  if (lane == 63) wt[w] = x;
  __syncthreads();
  int woff = 0;
#pragma unroll
  for (int k = 0; k < 4; ++k)
    if (k < w) woff += wt[k];
  int pos = part[blockIdx.x] + woff + ex;
#pragma unroll
  for (int k = 0; k < 4; ++k) {
    int idx = base + k;
    if (idx < n) off[idx] = pos;
    pos += c[k];
  }
}

__global__ __launch_bounds__(256) void fill_kernel(const int* __restrict__ ei,
                                                   const int* __restrict__ off,
                                                   int* __restrict__ cur,
                                                   int* __restrict__ srcs,
                                                   int base, int E) {
  int e = blockIdx.x * blockDim.x + threadIdx.x;
  if (e >= E) return;
  int s = ei[e], d = ei[E + e];
  int p = off[base + d] + atomicAdd(cur + base + d, 1);
  srcs[p] = s;
}

// ---- fused: h_new = LN(h_old + relu(sum_r mean_r + t + bls)) ----------------
__global__ __launch_bounds__(256) void gf_kernel(
    const ushort* __restrict__ g0, const ushort* __restrict__ g1,
    const ushort* __restrict__ g2, const int* __restrict__ srcs,
    const int* __restrict__ off, int b0_, int b1_, int b2_, int nrel,
    const ushort* __restrict__ t, const ushort* __restrict__ hold,
    ushort* __restrict__ hnew, const float* __restrict__ bls,
    const float* __restrict__ lng, const float* __restrict__ lnb, int ndst) {
  const int lane = threadIdx.x & 63;
  int wid = (blockIdx.x * blockDim.x + threadIdx.x) >> 6;
  const int nw = (gridDim.x * blockDim.x) >> 6;
  const float blv = bls[lane], gg = lng[lane], bb = lnb[lane];
  for (int d = wid; d < ndst; d += nw) {
    float o = 0.f;
    {
      int e0 = off[b0_ + d], e1 = off[b0_ + d + 1];
      float s = 0.f;
      for (int j = e0; j < e1; ++j) s += u2f(g0[(size_t)srcs[j] * 64 + lane]);
      o += s / fmaxf((float)(e1 - e0), 1.f);
    }
    if (nrel > 1) {
      int e0 = off[b1_ + d], e1 = off[b1_ + d + 1];
      float s = 0.f;
      for (int j = e0; j < e1; ++j) s += u2f(g1[(size_t)srcs[j] * 64 + lane]);
      o += s / fmaxf((float)(e1 - e0), 1.f);
    }
    if (nrel > 2) {
      int e0 = off[b2_ + d], e1 = off[b2_ + d + 1];
      float s = 0.f;
      for (int j = e0; j < e1; ++j) s += u2f(g2[(size_t)srcs[j] * 64 + lane]);
      o += s / fmaxf((float)(e1 - e0), 1.f);
    }
    float tv = u2f(t[(size_t)d * 64 + lane]);
    float hv = u2f(hold[(size_t)d * 64 + lane]);
    float v = hv + fmaxf(o + tv + blv, 0.f);
    float m = wave_sum(v) * (1.f / 64.f);
    float dd = v - m;
    float var = wave_sum(dd * dd) * (1.f / 64.f);
    hnew[(size_t)d * 64 + lane] = f2bf(dd * rsqrtf(var + 1e-5f) * gg + bb);
  }
}

// ---------------- pool ------------------------------------------------------
__global__ __launch_bounds__(64) void pool_kernel(
    const ushort* __restrict__ h, const int* __restrict__ batch,
    float* __restrict__ out, int n, int col_base) {
  const int lane = threadIdx.x;
  int gph = blockIdx.x >> 4;
  int s = blockIdx.x & 15;
  int lo = 0, hi = n;
  while (lo < hi) { int mid = (lo + hi) >> 1; if (batch[mid] < gph) lo = mid + 1; else hi = mid; }
  int beg = lo;
  hi = n;
  while (lo < hi) { int mid = (lo + hi) >> 1; if (batch[mid] < gph + 1) lo = mid + 1; else hi = mid; }
  int end = lo;
  int cnt = end - beg;
  if (cnt <= 0) return;
  int per = (cnt + POOL_SPLIT - 1) >> 4;
  int rb = beg + s * per;
  int re = min(rb + per, end);
  if (rb >= re) return;
  float acc = 0.f;
  for (int r = rb; r < re; ++r) acc += u2f(h[(size_t)r * 64 + lane]);
  unsafeAtomicAdd(out + gph * 192 + col_base + lane, acc);
}

__global__ __launch_bounds__(256) void pool_scale_kernel(
    float* __restrict__ out, const int* __restrict__ bp,
    const int* __restrict__ be, const int* __restrict__ bf,
    int np, int ne, int nf) {
  int idx = blockIdx.x * blockDim.x + threadIdx.x;
  if (idx >= 64 * 192) return;
  int gph = idx / 192, col = idx % 192;
  const int* b;
  int n;
  if (col < 64) { b = bp; n = np; }
  else if (col < 128) { b = be; n = ne; }
  else { b = bf; n = nf; }
  int lo = 0, hi = n;
  while (lo < hi) { int mid = (lo + hi) >> 1; if (b[mid] < gph) lo = mid + 1; else hi = mid; }
  int beg = lo;
  hi = n;
  while (lo < hi) { int mid = (lo + hi) >> 1; if (b[mid] < gph + 1) lo = mid + 1; else hi = mid; }
  int cnt = lo - beg;
  out[idx] = out[idx] / fmaxf((float)cnt, 1.f);
}

extern "C" void kernel_launch(void* const* d_in, const int* in_sizes, int n_in,
                              void* d_out, int out_size, void* d_ws, size_t ws_size,
                              hipStream_t stream) {
  const float* point_x = (const float*)d_in[0];
  const float* edge_x  = (const float*)d_in[1];
  const float* face_x  = (const float*)d_in[2];
  const int* bp = (const int*)d_in[3];
  const int* be = (const int*)d_in[4];
  const int* bf = (const int*)d_in[5];
  const int NP = in_sizes[3], NE = in_sizes[4], NF = in_sizes[5];
  const int Eg = in_sizes[6] / 2;

  const float* Wl  = (const float*)d_in[26];
  const float* blp = (const float*)d_in[27];
  const float* Wr  = (const float*)d_in[28];
  const float* lng = (const float*)d_in[29];
  const float* lnb = (const float*)d_in[30];

  // ---- workspace layout ----
  char* p = (char*)d_ws;
  ushort* hA = (ushort*)p; p += (size_t)(NP + NE + NF) * 64 * 2;
  ushort* hB = (ushort*)p; p += (size_t)(NP + NE + NF) * 64 * 2;
  ushort* g  = (ushort*)p; p += (size_t)(NP + NE + NE) * 64 * 2;
  ushort* tb = (ushort*)p; p += (size_t)NP * 64 * 2;
  ushort* fw = (ushort*)p; p += (size_t)25 * 4096 * 2;
  float* bls = (float*)p; p += 6 * 64 * 4;
  int* srcs = (int*)p; p += (size_t)8 * Eg * 4;
  const int NDSUM = 3 * NP + 3 * NF + 2 * NE;
  int* off = (int*)p; p += (size_t)(NDSUM + 1) * 4;
  int* cur = (int*)p; p += (size_t)NDSUM * 4;
  int* part = (int*)p; p += 4096;
  // total ~204 MB

  ushort* hptr[2][3];  // [set][type 0=p,1=e,2=f]
  hptr[0][0] = hA; hptr[0][1] = hA + (size_t)NP * 64; hptr[0][2] = hA + (size_t)(NP + NE) * 64;
  hptr[1][0] = hB; hptr[1][1] = hB + (size_t)NP * 64; hptr[1][2] = hB + (size_t)(NP + NE) * 64;
  ushort* gs[3] = {g, g + (size_t)NP * 64, g + (size_t)(NP + NE) * 64};

  // relations: 0 pp 1 fp 2 ep (dst P) | 3 pf 4 ef 5 ff (dst F) | 6 pe 7 fe (dst E)
  const int* ei[8] = {(const int*)d_in[6],  (const int*)d_in[7],
                      (const int*)d_in[8],  (const int*)d_in[9],
                      (const int*)d_in[10], (const int*)d_in[11],
                      (const int*)d_in[12], (const int*)d_in[13]};
  int ndst[8] = {NP, NP, NP, NF, NF, NF, NE, NE};
  int base[8];
  base[0] = 0;
  for (int r = 1; r < 8; ++r) base[r] = base[r - 1] + ndst[r - 1];

  // ---- CSR build (edge indices shared by both layers) ----
  const int cblk = (Eg + 255) / 256;
  hipMemsetAsync(cur, 0, (size_t)NDSUM * 4, stream);
  for (int r = 0; r < 8; ++r)
    count_kernel<<<cblk, 256, 0, stream>>>(ei[r] + Eg, cur + base[r], Eg);
  const int nb = (NDSUM + 1023) / 1024;
  scan1_kernel<<<nb, 256, 0, stream>>>(cur, part, NDSUM);
  scan2_kernel<<<1, 1024, 0, stream>>>(part, off, nb, NDSUM, 8 * Eg);
  scan3_kernel<<<nb, 256, 0, stream>>>(cur, part, off, NDSUM);
  hipMemsetAsync(cur, 0, (size_t)NDSUM * 4, stream);
  for (int r = 0; r < 8; ++r)
    fill_kernel<<<cblk, 256, 0, stream>>>(ei[r], off, cur, srcs, base[r], Eg);

  // ---- weight prep ----
  prep_kernel<<<(25 * 4096 + 6 * 64 + 255) / 256, 256, 0, stream>>>(
      Wl, Wr, blp, (const float*)d_in[16], (const float*)d_in[20],
      (const float*)d_in[24], fw, bls);

  auto gblk = [](int n) { return ((n + 31) / 32 + 3) / 4; };

  // ---- input MLPs (stage1 VALU -> staging, stage2 MFMA -> hA) ----
  mlp1_kernel<3><<<1024, 256, 0, stream>>>(point_x, (const float*)d_in[14],
      (const float*)d_in[15], gs[0], NP);
  gemm_mfma_kernel<<<gblk(NP), 256, 0, stream>>>(gs[0], fw + 22 * 4096,
      (const float*)d_in[17], hptr[0][0], NP);
  mlp1_kernel<2><<<1024, 256, 0, stream>>>(edge_x, (const float*)d_in[18],
      (const float*)d_in[19], gs[0], NE);
  gemm_mfma_kernel<<<gblk(NE), 256, 0, stream>>>(gs[0], fw + 23 * 4096,
      (const float*)d_in[21], hptr[0][1], NE);
  mlp1_kernel<16><<<1024, 256, 0, stream>>>(face_x, (const float*)d_in[22],
      (const float*)d_in[23], gs[0], NF);
  gemm_mfma_kernel<<<gblk(NF), 256, 0, stream>>>(gs[0], fw + 24 * 4096,
      (const float*)d_in[25], hptr[0][2], NF);

  // ---- 2 hetero-SAGE layers (read set cs, write set ns) ----
  int cs = 0;
  for (int i = 0; i < 2; ++i) {
    int ns = cs ^ 1;
    // point (t=0): rels 0(src p),1(src f),2(src e)
    gemm_mfma_kernel<<<gblk(NP), 256, 0, stream>>>(hptr[cs][0], fw + (size_t)(i * 8 + 0) * 4096, nullptr, gs[0], NP);
    gemm_mfma_kernel<<<gblk(NF), 256, 0, stream>>>(hptr[cs][2], fw + (size_t)(i * 8 + 1) * 4096, nullptr, gs[1], NF);
    gemm_mfma_kernel<<<gblk(NE), 256, 0, stream>>>(hptr[cs][1], fw + (size_t)(i * 8 + 2) * 4096, nullptr, gs[2], NE);
    gemm_mfma_kernel<<<gblk(NP), 256, 0, stream>>>(hptr[cs][0], fw + (size_t)(16 + i * 3 + 0) * 4096, nullptr, tb, NP);
    gf_kernel<<<2048, 256, 0, stream>>>(gs[0], gs[1], gs[2], srcs, off,
        base[0], base[1], base[2], 3, tb, hptr[cs][0], hptr[ns][0],
        bls + (i * 3 + 0) * 64, lng + (i * 3 + 0) * 64, lnb + (i * 3 + 0) * 64, NP);
    // face (t=2): rels 3(src p),4(src e),5(src f)
    gemm_mfma_kernel<<<gblk(NP), 256, 0, stream>>>(hptr[cs][0], fw + (size_t)(i * 8 + 3) * 4096, nullptr, gs[0], NP);
    gemm_mfma_kernel<<<gblk(NE), 256, 0, stream>>>(hptr[cs][1], fw + (size_t)(i * 8 + 4) * 4096, nullptr, gs[1], NE);
    gemm_mfma_kernel<<<gblk(NF), 256, 0, stream>>>(hptr[cs][2], fw + (size_t)(i * 8 + 5) * 4096, nullptr, gs[2], NF);
    gemm_mfma_kernel<<<gblk(NF), 256, 0, stream>>>(hptr[cs][2], fw + (size_t)(16 + i * 3 + 2) * 4096, nullptr, tb, NF);
    gf_kernel<<<2048, 256, 0, stream>>>(gs[0], gs[1], gs[2], srcs, off,
        base[3], base[4], base[5], 3, tb, hptr[cs][2], hptr[ns][2],
        bls + (i * 3 + 2) * 64, lng + (i * 3 + 2) * 64, lnb + (i * 3 + 2) * 64, NF);
    // edge (t=1): rels 6(src p),7(src f)
    gemm_mfma_kernel<<<gblk(NP), 256, 0, stream>>>(hptr[cs][0], fw + (size_t)(i * 8 + 6) * 4096, nullptr, gs[0], NP);
    gemm_mfma_kernel<<<gblk(NF), 256, 0, stream>>>(hptr[cs][2], fw + (size_t)(i * 8 + 7) * 4096, nullptr, gs[1], NF);
    gemm_mfma_kernel<<<gblk(NE), 256, 0, stream>>>(hptr[cs][1], fw + (size_t)(16 + i * 3 + 1) * 4096, nullptr, tb, NE);
    gf_kernel<<<2048, 256, 0, stream>>>(gs[0], gs[1], nullptr, srcs, off,
        base[6], base[7], 0, 2, tb, hptr[cs][1], hptr[ns][1],
        bls + (i * 3 + 1) * 64, lng + (i * 3 + 1) * 64, lnb + (i * 3 + 1) * 64, NE);
    cs = ns;
  }

  // ---- pool + scale ----
  float* out = (float*)d_out;
  hipMemsetAsync(out, 0, (size_t)out_size * sizeof(float), stream);
  pool_kernel<<<64 * POOL_SPLIT, 64, 0, stream>>>(hptr[cs][0], bp, out, NP, 0);
  pool_kernel<<<64 * POOL_SPLIT, 64, 0, stream>>>(hptr[cs][1], be, out, NE, 64);
  pool_kernel<<<64 * POOL_SPLIT, 64, 0, stream>>>(hptr[cs][2], bf, out, NF, 128);
  pool_scale_kernel<<<(64 * 192 + 255) / 256, 256, 0, stream>>>(out, bp, be, bf, NP, NE, NF);
}

// Round 4
// 1344.427 us; speedup vs baseline: 7.0977x; 1.1892x over previous
//
#include <hip/hip_runtime.h>
#include <hip/hip_bf16.h>

// CADTopoEncoder: hetero-GNN (point/edge/face), 2 SAGE layers + LN + pool.
// bf16 hidden state (double-buffered); all 64x64 matmuls via mfma_f32_16x16x32_bf16
// (batched multi-job kernel); CSR gather fused with residual+ReLU+LN, vectorized
// 8 edges x 8 lanes x 16B per gather instruction.

#define POOL_SPLIT 16

typedef __attribute__((ext_vector_type(8))) short bf8_t;   // 8 bf16 in 4 VGPRs
typedef __attribute__((ext_vector_type(4))) float f32x4;

__device__ __forceinline__ ushort f2bf(float f) {
  union { __hip_bfloat16 b; ushort u; } v;
  v.b = __float2bfloat16(f);
  return v.u;
}
__device__ __forceinline__ float u2f(ushort u) {
  union { ushort u; __hip_bfloat16 b; } v;
  v.u = u;
  return __bfloat162float(v.b);
}

// ---------------- prep: weights -> bf16 MFMA fragment order, summed biases ----
// fw holds 25 matrices (4096 bf16 each): m 0..15 Wl[i*8+rel]; 16..21 Wrs per
// (layer,type); 22..24 mlp w2 p/e/f.
__global__ __launch_bounds__(256) void prep_kernel(
    const float* __restrict__ Wl, const float* __restrict__ Wr,
    const float* __restrict__ bl, const float* __restrict__ w2p,
    const float* __restrict__ w2e, const float* __restrict__ w2f,
    ushort* __restrict__ fw, float* __restrict__ bls) {
  int idx = blockIdx.x * blockDim.x + threadIdx.x;
  if (idx < 25 * 4096) {
    int m = idx >> 12, e = idx & 4095;
    int i8 = e >> 3, b = e & 7;
    int lane = i8 & 63, cb = i8 >> 6;
    int ks = cb & 1, ct = cb >> 1;
    int k = ks * 32 + ((lane >> 4) << 3) + b;
    int col = (ct << 4) + (lane & 15);
    int widx = (k << 6) + col;
    float v;
    if (m < 16) {
      v = Wl[(size_t)m * 4096 + widx];
    } else if (m < 22) {
      int c = m - 16, i = c / 3, t = c % 3;
      int rb = (t == 0) ? 0 : ((t == 1) ? 6 : 3);
      int rc = (t == 1) ? 2 : 3;
      v = 0.f;
      for (int r = 0; r < rc; ++r) v += Wr[(size_t)(i * 8 + rb + r) * 4096 + widx];
    } else {
      const float* w2 = (m == 22) ? w2p : ((m == 23) ? w2e : w2f);
      v = w2[widx];
    }
    fw[idx] = f2bf(v);
  } else if (idx < 25 * 4096 + 6 * 64) {
    int j = idx - 25 * 4096;
    int c = j >> 6, e = j & 63;
    int i = c / 3, t = c % 3;
    int rb = (t == 0) ? 0 : ((t == 1) ? 6 : 3);
    int rc = (t == 1) ? 2 : 3;
    float s = 0.f;
    for (int r = 0; r < rc; ++r) s += bl[(i * 8 + rb + r) * 64 + e];
    bls[c * 64 + e] = s;
  }
}

// ---------------- batched MFMA GEMM: C[n,64](bf16) = A[n,64](bf16) @ W (+bias) ----
struct GJob { const ushort* A; const ushort* W; const float* bias; ushort* C; int n; };
struct GJobs { GJob j0, j1, j2, j3; };

__global__ __launch_bounds__(256) void gemm_multi_kernel(GJobs js) {
  GJob jb = (blockIdx.y == 0) ? js.j0
          : (blockIdx.y == 1) ? js.j1
          : (blockIdx.y == 2) ? js.j2 : js.j3;
  const int n = jb.n;
  const int lane = threadIdx.x & 63;
  const int wid = (blockIdx.x * blockDim.x + threadIdx.x) >> 6;
  const int r0 = wid * 32;
  if (r0 >= n) return;
  bf8_t bw[8];
#pragma unroll
  for (int i = 0; i < 8; ++i)
    bw[i] = *(const bf8_t*)(jb.W + ((i << 6) + lane) * 8);
  const int koff = ((lane >> 4) << 3);
  int ra = r0 + (lane & 15);
  int rb = ra + 16;
  ra = min(ra, n - 1);
  rb = min(rb, n - 1);
  const bf8_t a00 = *(const bf8_t*)(jb.A + (size_t)ra * 64 + koff);
  const bf8_t a01 = *(const bf8_t*)(jb.A + (size_t)ra * 64 + 32 + koff);
  const bf8_t a10 = *(const bf8_t*)(jb.A + (size_t)rb * 64 + koff);
  const bf8_t a11 = *(const bf8_t*)(jb.A + (size_t)rb * 64 + 32 + koff);
  f32x4 acc[8];
#pragma unroll
  for (int i = 0; i < 8; ++i) acc[i] = (f32x4){0.f, 0.f, 0.f, 0.f};
#pragma unroll
  for (int ct = 0; ct < 4; ++ct) {
    acc[ct]     = __builtin_amdgcn_mfma_f32_16x16x32_bf16(a00, bw[ct * 2 + 0], acc[ct], 0, 0, 0);
    acc[ct]     = __builtin_amdgcn_mfma_f32_16x16x32_bf16(a01, bw[ct * 2 + 1], acc[ct], 0, 0, 0);
    acc[4 + ct] = __builtin_amdgcn_mfma_f32_16x16x32_bf16(a10, bw[ct * 2 + 0], acc[4 + ct], 0, 0, 0);
    acc[4 + ct] = __builtin_amdgcn_mfma_f32_16x16x32_bf16(a11, bw[ct * 2 + 1], acc[4 + ct], 0, 0, 0);
  }
  float bv[4] = {0.f, 0.f, 0.f, 0.f};
  if (jb.bias) {
#pragma unroll
    for (int ct = 0; ct < 4; ++ct) bv[ct] = jb.bias[ct * 16 + (lane & 15)];
  }
  const int rowb = r0 + ((lane >> 4) << 2);
  const int cb = lane & 15;
#pragma unroll
  for (int rt = 0; rt < 2; ++rt) {
#pragma unroll
    for (int q = 0; q < 4; ++q) {
      int row = rowb + rt * 16 + q;
      if (row < n) {
#pragma unroll
        for (int ct = 0; ct < 4; ++ct)
          jb.C[(size_t)row * 64 + ct * 16 + cb] = f2bf(acc[rt * 4 + ct][q] + bv[ct]);
      }
    }
  }
}

// ---------------- mlp stage 1: h1 = relu(x@w1+b1) -> bf16 --------------------
template <int FIN>
__global__ __launch_bounds__(256) void mlp1_kernel(
    const float* __restrict__ x, const float* __restrict__ w1,
    const float* __restrict__ b1, ushort* __restrict__ h1, int n) {
  const int lane = threadIdx.x & 63;
  int wid = (blockIdx.x * blockDim.x + threadIdx.x) >> 6;
  const int nw = (gridDim.x * blockDim.x) >> 6;
  float w1c[FIN];
#pragma unroll
  for (int k = 0; k < FIN; ++k) w1c[k] = w1[k * 64 + lane];
  const float b1v = b1[lane];
  for (int r = wid; r < n; r += nw) {
    float s = b1v;
#pragma unroll
    for (int k = 0; k < FIN; ++k) s = fmaf(x[(size_t)r * FIN + k], w1c[k], s);
    h1[(size_t)r * 64 + lane] = f2bf(fmaxf(s, 0.f));
  }
}

// ---------------- CSR build (merged over 8 relations) ------------------------
struct EIPack {
  const int* e0; const int* e1; const int* e2; const int* e3;
  const int* e4; const int* e5; const int* e6; const int* e7;
  int b0, b1, b2, b3, b4, b5, b6, b7;
};

__device__ __forceinline__ void ei_sel(const EIPack& t, int r, const int*& ei, int& b) {
  switch (r) {
    case 0: ei = t.e0; b = t.b0; break;
    case 1: ei = t.e1; b = t.b1; break;
    case 2: ei = t.e2; b = t.b2; break;
    case 3: ei = t.e3; b = t.b3; break;
    case 4: ei = t.e4; b = t.b4; break;
    case 5: ei = t.e5; b = t.b5; break;
    case 6: ei = t.e6; b = t.b6; break;
    default: ei = t.e7; b = t.b7; break;
  }
}

__global__ __launch_bounds__(256) void count8_kernel(EIPack t, int* __restrict__ cur,
                                                     int E, int cblk) {
  int r = blockIdx.x / cblk;
  int e = (blockIdx.x - r * cblk) * 256 + threadIdx.x;
  if (e >= E) return;
  const int* ei; int b;
  ei_sel(t, r, ei, b);
  atomicAdd(cur + b + ei[E + e], 1);
}

__global__ __launch_bounds__(256) void fill8_kernel(EIPack t, const int* __restrict__ off,
                                                    int* __restrict__ cur,
                                                    int* __restrict__ srcs, int E, int cblk) {
  int r = blockIdx.x / cblk;
  int e = (blockIdx.x - r * cblk) * 256 + threadIdx.x;
  if (e >= E) return;
  const int* ei; int b;
  ei_sel(t, r, ei, b);
  int s = ei[e], d = ei[E + e];
  int p = off[b + d] + atomicAdd(cur + b + d, 1);
  srcs[p] = s;
}

__global__ __launch_bounds__(256) void scan1_kernel(const int* __restrict__ cnt,
                                                    int* __restrict__ part, int n) {
  __shared__ int wt[4];
  int base = blockIdx.x * 1024;
  int t = 0;
  for (int i = threadIdx.x; i < 1024; i += 256) {
    int idx = base + i;
    if (idx < n) t += cnt[idx];
  }
#pragma unroll
  for (int d = 32; d > 0; d >>= 1) t += __shfl_xor(t, d, 64);
  if ((threadIdx.x & 63) == 0) wt[threadIdx.x >> 6] = t;
  __syncthreads();
  if (threadIdx.x == 0) part[blockIdx.x] = wt[0] + wt[1] + wt[2] + wt[3];
}

__global__ __launch_bounds__(1024) void scan2_kernel(int* __restrict__ part,
                                                     int* __restrict__ off, int nb,
                                                     int n, int total) {
  __shared__ int lds[1024];
  int tid = threadIdx.x;
  int v = (tid < nb) ? part[tid] : 0;
  lds[tid] = v;
  __syncthreads();
  for (int d = 1; d < 1024; d <<= 1) {
    int y = (tid >= d) ? lds[tid - d] : 0;
    __syncthreads();
    lds[tid] += y;
    __syncthreads();
  }
  if (tid < nb) part[tid] = lds[tid] - v;  // exclusive
  if (tid == 0) off[n] = total;
}

__global__ __launch_bounds__(256) void scan3_kernel(const int* __restrict__ cnt,
                                                    const int* __restrict__ part,
                                                    int* __restrict__ off, int n) {
  __shared__ int wt[4];
  int base = blockIdx.x * 1024 + threadIdx.x * 4;
  int c[4];
#pragma unroll
  for (int k = 0; k < 4; ++k) {
    int idx = base + k;
    c[k] = (idx < n) ? cnt[idx] : 0;
  }
  int t = c[0] + c[1] + c[2] + c[3];
  int lane = threadIdx.x & 63, w = threadIdx.x >> 6;
  int x = t;
#pragma unroll
  for (int d = 1; d < 64; d <<= 1) {
    int y = __shfl_up(x, d, 64);
    if (lane >= d) x += y;
  }
  int ex = x - t;
  if (lane == 63) wt[w] = x;
  __syncthreads();
  int woff = 0;
#pragma unroll
  for (int k = 0; k < 4; ++k)
    if (k < w) woff += wt[k];
  int pos = part[blockIdx.x] + woff + ex;
#pragma unroll
  for (int k = 0; k < 4; ++k) {
    int idx = base + k;
    if (idx < n) off[idx] = pos;
    pos += c[k];
  }
}

// ---- fused gather+final: h_new = LN(h_old + relu(sum_r mean_r + t + bls)) ----
// lane = g8*8 + l8 : g8 = edge slot (8 edges/iter), l8 = column octet (16B/lane).
__device__ __forceinline__ void gather_rel(const ushort* __restrict__ g,
    const int* __restrict__ srcs, const int* __restrict__ off, int bofs, int d,
    int g8, int l8, float o[8]) {
  int e0 = off[bofs + d], e1 = off[bofs + d + 1];
  float inv = 1.f / fmaxf((float)(e1 - e0), 1.f);
  for (int j = e0 + g8; j < e1; j += 8) {
    int s = srcs[j];
    bf8_t v = *(const bf8_t*)(g + (size_t)s * 64 + l8 * 8);
#pragma unroll
    for (int c = 0; c < 8; ++c) o[c] = fmaf(u2f((ushort)v[c]), inv, o[c]);
  }
}

__global__ __launch_bounds__(256) void gf_kernel(
    const ushort* __restrict__ g0, const ushort* __restrict__ g1,
    const ushort* __restrict__ g2, const int* __restrict__ srcs,
    const int* __restrict__ off, int b0_, int b1_, int b2_, int nrel,
    const ushort* __restrict__ t, const ushort* __restrict__ hold,
    ushort* __restrict__ hnew, const float* __restrict__ bls,
    const float* __restrict__ lng, const float* __restrict__ lnb, int ndst) {
  const int lane = threadIdx.x & 63;
  const int l8 = lane & 7, g8 = lane >> 3;
  int wid = (blockIdx.x * blockDim.x + threadIdx.x) >> 6;
  const int nw = (gridDim.x * blockDim.x) >> 6;
  float blr[8], ggr[8], bbr[8];
  *(float4*)(blr)     = *(const float4*)(bls + l8 * 8);
  *(float4*)(blr + 4) = *(const float4*)(bls + l8 * 8 + 4);
  *(float4*)(ggr)     = *(const float4*)(lng + l8 * 8);
  *(float4*)(ggr + 4) = *(const float4*)(lng + l8 * 8 + 4);
  *(float4*)(bbr)     = *(const float4*)(lnb + l8 * 8);
  *(float4*)(bbr + 4) = *(const float4*)(lnb + l8 * 8 + 4);
  for (int d = wid; d < ndst; d += nw) {
    float o[8];
#pragma unroll
    for (int c = 0; c < 8; ++c) o[c] = 0.f;
    gather_rel(g0, srcs, off, b0_, d, g8, l8, o);
    if (nrel > 1) gather_rel(g1, srcs, off, b1_, d, g8, l8, o);
    if (nrel > 2) gather_rel(g2, srcs, off, b2_, d, g8, l8, o);
    // reduce edge-slot groups (g8) -> every lane holds full per-column sums
#pragma unroll
    for (int c = 0; c < 8; ++c) {
      o[c] += __shfl_xor(o[c], 8, 64);
      o[c] += __shfl_xor(o[c], 16, 64);
      o[c] += __shfl_xor(o[c], 32, 64);
    }
    bf8_t tv = *(const bf8_t*)(t + (size_t)d * 64 + l8 * 8);
    bf8_t hv = *(const bf8_t*)(hold + (size_t)d * 64 + l8 * 8);
    float v[8];
    float s = 0.f;
#pragma unroll
    for (int c = 0; c < 8; ++c) {
      float x = u2f((ushort)hv[c]) + fmaxf(o[c] + u2f((ushort)tv[c]) + blr[c], 0.f);
      v[c] = x;
      s += x;
    }
    s += __shfl_xor(s, 1, 64);
    s += __shfl_xor(s, 2, 64);
    s += __shfl_xor(s, 4, 64);
    float m = s * (1.f / 64.f);
    float vs = 0.f;
#pragma unroll
    for (int c = 0; c < 8; ++c) {
      float dd = v[c] - m;
      vs += dd * dd;
    }
    vs += __shfl_xor(vs, 1, 64);
    vs += __shfl_xor(vs, 2, 64);
    vs += __shfl_xor(vs, 4, 64);
    float rstd = rsqrtf(vs * (1.f / 64.f) + 1e-5f);
    if (g8 == 0) {
      bf8_t outv;
#pragma unroll
      for (int c = 0; c < 8; ++c)
        outv[c] = (short)f2bf((v[c] - m) * rstd * ggr[c] + bbr[c]);
      *(bf8_t*)(hnew + (size_t)d * 64 + l8 * 8) = outv;
    }
  }
}

// ---------------- pool ------------------------------------------------------
__global__ __launch_bounds__(64) void pool_kernel(
    const ushort* __restrict__ h, const int* __restrict__ batch,
    float* __restrict__ out, int n, int col_base) {
  const int lane = threadIdx.x;
  int gph = blockIdx.x >> 4;
  int s = blockIdx.x & 15;
  int lo = 0, hi = n;
  while (lo < hi) { int mid = (lo + hi) >> 1; if (batch[mid] < gph) lo = mid + 1; else hi = mid; }
  int beg = lo;
  hi = n;
  while (lo < hi) { int mid = (lo + hi) >> 1; if (batch[mid] < gph + 1) lo = mid + 1; else hi = mid; }
  int end = lo;
  int cnt = end - beg;
  if (cnt <= 0) return;
  int per = (cnt + POOL_SPLIT - 1) >> 4;
  int rb = beg + s * per;
  int re = min(rb + per, end);
  if (rb >= re) return;
  float acc = 0.f;
  for (int r = rb; r < re; ++r) acc += u2f(h[(size_t)r * 64 + lane]);
  unsafeAtomicAdd(out + gph * 192 + col_base + lane, acc);
}

__global__ __launch_bounds__(256) void pool_scale_kernel(
    float* __restrict__ out, const int* __restrict__ bp,
    const int* __restrict__ be, const int* __restrict__ bf,
    int np, int ne, int nf) {
  int idx = blockIdx.x * blockDim.x + threadIdx.x;
  if (idx >= 64 * 192) return;
  int gph = idx / 192, col = idx % 192;
  const int* b;
  int n;
  if (col < 64) { b = bp; n = np; }
  else if (col < 128) { b = be; n = ne; }
  else { b = bf; n = nf; }
  int lo = 0, hi = n;
  while (lo < hi) { int mid = (lo + hi) >> 1; if (b[mid] < gph) lo = mid + 1; else hi = mid; }
  int beg = lo;
  hi = n;
  while (lo < hi) { int mid = (lo + hi) >> 1; if (b[mid] < gph + 1) lo = mid + 1; else hi = mid; }
  int cnt = lo - beg;
  out[idx] = out[idx] / fmaxf((float)cnt, 1.f);
}

extern "C" void kernel_launch(void* const* d_in, const int* in_sizes, int n_in,
                              void* d_out, int out_size, void* d_ws, size_t ws_size,
                              hipStream_t stream) {
  const float* point_x = (const float*)d_in[0];
  const float* edge_x  = (const float*)d_in[1];
  const float* face_x  = (const float*)d_in[2];
  const int* bp = (const int*)d_in[3];
  const int* be = (const int*)d_in[4];
  const int* bf = (const int*)d_in[5];
  const int NP = in_sizes[3], NE = in_sizes[4], NF = in_sizes[5];
  const int Eg = in_sizes[6] / 2;

  const float* Wl  = (const float*)d_in[26];
  const float* blp = (const float*)d_in[27];
  const float* Wr  = (const float*)d_in[28];
  const float* lng = (const float*)d_in[29];
  const float* lnb = (const float*)d_in[30];

  // ---- workspace layout ----
  char* p = (char*)d_ws;
  ushort* hA = (ushort*)p; p += (size_t)(NP + NE + NF) * 64 * 2;
  ushort* hB = (ushort*)p; p += (size_t)(NP + NE + NF) * 64 * 2;
  ushort* g  = (ushort*)p; p += (size_t)(NP + NE + NE) * 64 * 2;
  ushort* tb = (ushort*)p; p += (size_t)NP * 64 * 2;
  ushort* fw = (ushort*)p; p += (size_t)25 * 4096 * 2;
  float* bls = (float*)p; p += 6 * 64 * 4;
  int* srcs = (int*)p; p += (size_t)8 * Eg * 4;
  const int NDSUM = 3 * NP + 3 * NF + 2 * NE;
  int* off = (int*)p; p += (size_t)(NDSUM + 1) * 4;
  int* cur = (int*)p; p += (size_t)NDSUM * 4;
  int* part = (int*)p; p += 4096;

  ushort* hptr[2][3];  // [set][type 0=p,1=e,2=f]
  hptr[0][0] = hA; hptr[0][1] = hA + (size_t)NP * 64; hptr[0][2] = hA + (size_t)(NP + NE) * 64;
  hptr[1][0] = hB; hptr[1][1] = hB + (size_t)NP * 64; hptr[1][2] = hB + (size_t)(NP + NE) * 64;
  ushort* gs[3] = {g, g + (size_t)NP * 64, g + (size_t)(NP + NE) * 64};

  // relations: 0 pp 1 fp 2 ep (dst P) | 3 pf 4 ef 5 ff (dst F) | 6 pe 7 fe (dst E)
  const int* ei[8] = {(const int*)d_in[6],  (const int*)d_in[7],
                      (const int*)d_in[8],  (const int*)d_in[9],
                      (const int*)d_in[10], (const int*)d_in[11],
                      (const int*)d_in[12], (const int*)d_in[13]};
  int ndst[8] = {NP, NP, NP, NF, NF, NF, NE, NE};
  int base[8];
  base[0] = 0;
  for (int r = 1; r < 8; ++r) base[r] = base[r - 1] + ndst[r - 1];

  EIPack ep;
  ep.e0 = ei[0]; ep.e1 = ei[1]; ep.e2 = ei[2]; ep.e3 = ei[3];
  ep.e4 = ei[4]; ep.e5 = ei[5]; ep.e6 = ei[6]; ep.e7 = ei[7];
  ep.b0 = base[0]; ep.b1 = base[1]; ep.b2 = base[2]; ep.b3 = base[3];
  ep.b4 = base[4]; ep.b5 = base[5]; ep.b6 = base[6]; ep.b7 = base[7];

  // ---- CSR build (edge indices shared by both layers) ----
  const int cblk = (Eg + 255) / 256;
  hipMemsetAsync(cur, 0, (size_t)NDSUM * 4, stream);
  count8_kernel<<<8 * cblk, 256, 0, stream>>>(ep, cur, Eg, cblk);
  const int nb = (NDSUM + 1023) / 1024;
  scan1_kernel<<<nb, 256, 0, stream>>>(cur, part, NDSUM);
  scan2_kernel<<<1, 1024, 0, stream>>>(part, off, nb, NDSUM, 8 * Eg);
  scan3_kernel<<<nb, 256, 0, stream>>>(cur, part, off, NDSUM);
  hipMemsetAsync(cur, 0, (size_t)NDSUM * 4, stream);
  fill8_kernel<<<8 * cblk, 256, 0, stream>>>(ep, off, cur, srcs, Eg, cblk);

  // ---- weight prep ----
  prep_kernel<<<(25 * 4096 + 6 * 64 + 255) / 256, 256, 0, stream>>>(
      Wl, Wr, blp, (const float*)d_in[16], (const float*)d_in[20],
      (const float*)d_in[24], fw, bls);

  auto gblk = [](int n) { return ((n + 31) / 32 + 3) / 4; };
  auto launch_gemm = [&](GJob a, GJob b, GJob c, GJob d, int cnt) {
    GJobs js;
    js.j0 = a; js.j1 = b; js.j2 = c; js.j3 = d;
    int mx = gblk(a.n);
    mx = max(mx, gblk(b.n));
    if (cnt > 2) mx = max(mx, gblk(c.n));
    if (cnt > 3) mx = max(mx, gblk(d.n));
    gemm_multi_kernel<<<dim3(mx, cnt), 256, 0, stream>>>(js);
  };

  // ---- input MLPs (stage1 VALU -> staging, stage2 batched MFMA -> hA) ----
  mlp1_kernel<3><<<1024, 256, 0, stream>>>(point_x, (const float*)d_in[14],
      (const float*)d_in[15], gs[0], NP);
  mlp1_kernel<2><<<1024, 256, 0, stream>>>(edge_x, (const float*)d_in[18],
      (const float*)d_in[19], gs[1], NE);
  mlp1_kernel<16><<<1024, 256, 0, stream>>>(face_x, (const float*)d_in[22],
      (const float*)d_in[23], gs[2], NF);
  launch_gemm({gs[0], fw + 22 * 4096, (const float*)d_in[17], hptr[0][0], NP},
              {gs[1], fw + 23 * 4096, (const float*)d_in[21], hptr[0][1], NE},
              {gs[2], fw + 24 * 4096, (const float*)d_in[25], hptr[0][2], NF},
              {gs[2], fw + 24 * 4096, nullptr, hptr[0][2], 0}, 3);

  // ---- 2 hetero-SAGE layers (read set cs, write set ns) ----
  int cs = 0;
  for (int i = 0; i < 2; ++i) {
    int ns = cs ^ 1;
    ushort* hp_ = hptr[cs][0];
    ushort* he_ = hptr[cs][1];
    ushort* hf_ = hptr[cs][2];
    // point phase: rels 0(src p),1(src f),2(src e) + t = hp@Wrs
    launch_gemm({hp_, fw + (size_t)(i * 8 + 0) * 4096, nullptr, gs[0], NP},
                {hf_, fw + (size_t)(i * 8 + 1) * 4096, nullptr, gs[1], NF},
                {he_, fw + (size_t)(i * 8 + 2) * 4096, nullptr, gs[2], NE},
                {hp_, fw + (size_t)(16 + i * 3 + 0) * 4096, nullptr, tb, NP}, 4);
    gf_kernel<<<2048, 256, 0, stream>>>(gs[0], gs[1], gs[2], srcs, off,
        base[0], base[1], base[2], 3, tb, hp_, hptr[ns][0],
        bls + (i * 3 + 0) * 64, lng + (i * 3 + 0) * 64, lnb + (i * 3 + 0) * 64, NP);
    // face phase: rels 3(src p),4(src e),5(src f) + t = hf@Wrs
    launch_gemm({hp_, fw + (size_t)(i * 8 + 3) * 4096, nullptr, gs[0], NP},
                {he_, fw + (size_t)(i * 8 + 4) * 4096, nullptr, gs[1], NE},
                {hf_, fw + (size_t)(i * 8 + 5) * 4096, nullptr, gs[2], NF},
                {hf_, fw + (size_t)(16 + i * 3 + 2) * 4096, nullptr, tb, NF}, 4);
    gf_kernel<<<2048, 256, 0, stream>>>(gs[0], gs[1], gs[2], srcs, off,
        base[3], base[4], base[5], 3, tb, hf_, hptr[ns][2],
        bls + (i * 3 + 2) * 64, lng + (i * 3 + 2) * 64, lnb + (i * 3 + 2) * 64, NF);
    // edge phase: rels 6(src p),7(src f) + t = he@Wrs
    launch_gemm({hp_, fw + (size_t)(i * 8 + 6) * 4096, nullptr, gs[0], NP},
                {hf_, fw + (size_t)(i * 8 + 7) * 4096, nullptr, gs[1], NF},
                {he_, fw + (size_t)(16 + i * 3 + 1) * 4096, nullptr, tb, NE},
                {he_, fw + (size_t)(16 + i * 3 + 1) * 4096, nullptr, tb, 0}, 3);
    gf_kernel<<<2048, 256, 0, stream>>>(gs[0], gs[1], nullptr, srcs, off,
        base[6], base[7], 0, 2, tb, he_, hptr[ns][1],
        bls + (i * 3 + 1) * 64, lng + (i * 3 + 1) * 64, lnb + (i * 3 + 1) * 64, NE);
    cs = ns;
  }

  // ---- pool + scale ----
  float* out = (float*)d_out;
  hipMemsetAsync(out, 0, (size_t)out_size * sizeof(float), stream);
  pool_kernel<<<64 * POOL_SPLIT, 64, 0, stream>>>(hptr[cs][0], bp, out, NP, 0);
  pool_kernel<<<64 * POOL_SPLIT, 64, 0, stream>>>(hptr[cs][1], be, out, NE, 64);
  pool_kernel<<<64 * POOL_SPLIT, 64, 0, stream>>>(hptr[cs][2], bf, out, NF, 128);
  pool_scale_kernel<<<(64 * 192 + 255) / 256, 256, 0, stream>>>(out, bp, be, bf, NP, NE, NF);
}

// Round 5
// 999.075 us; speedup vs baseline: 9.5511x; 1.3457x over previous
//
#include <hip/hip_runtime.h>
#include <hip/hip_bf16.h>

// CADTopoEncoder: hetero-GNN (point/edge/face), 2 SAGE layers + LN + pool.
// bf16 hidden state (double-buffered); all 64x64 matmuls via mfma_f32_16x16x32_bf16
// (batched multi-job kernel); CSR gather fused with residual+ReLU+LN.
// gf: one dst row per 8-lane group (no cross-group reduce, contiguous row writes).

#define POOL_SPLIT 16

typedef __attribute__((ext_vector_type(8))) short bf8_t;   // 8 bf16 in 4 VGPRs
typedef __attribute__((ext_vector_type(4))) float f32x4;

__device__ __forceinline__ ushort f2bf(float f) {
  union { __hip_bfloat16 b; ushort u; } v;
  v.b = __float2bfloat16(f);
  return v.u;
}
__device__ __forceinline__ float u2f(ushort u) {
  union { ushort u; __hip_bfloat16 b; } v;
  v.u = u;
  return __bfloat162float(v.b);
}

// ---------------- prep: weights -> bf16 MFMA fragment order, summed biases ----
// fw holds 25 matrices (4096 bf16 each): m 0..15 Wl[i*8+rel]; 16..21 Wrs per
// (layer,type); 22..24 mlp w2 p/e/f.
__global__ __launch_bounds__(256) void prep_kernel(
    const float* __restrict__ Wl, const float* __restrict__ Wr,
    const float* __restrict__ bl, const float* __restrict__ w2p,
    const float* __restrict__ w2e, const float* __restrict__ w2f,
    ushort* __restrict__ fw, float* __restrict__ bls) {
  int idx = blockIdx.x * blockDim.x + threadIdx.x;
  if (idx < 25 * 4096) {
    int m = idx >> 12, e = idx & 4095;
    int i8 = e >> 3, b = e & 7;
    int lane = i8 & 63, cb = i8 >> 6;
    int ks = cb & 1, ct = cb >> 1;
    int k = ks * 32 + ((lane >> 4) << 3) + b;
    int col = (ct << 4) + (lane & 15);
    int widx = (k << 6) + col;
    float v;
    if (m < 16) {
      v = Wl[(size_t)m * 4096 + widx];
    } else if (m < 22) {
      int c = m - 16, i = c / 3, t = c % 3;
      int rb = (t == 0) ? 0 : ((t == 1) ? 6 : 3);
      int rc = (t == 1) ? 2 : 3;
      v = 0.f;
      for (int r = 0; r < rc; ++r) v += Wr[(size_t)(i * 8 + rb + r) * 4096 + widx];
    } else {
      const float* w2 = (m == 22) ? w2p : ((m == 23) ? w2e : w2f);
      v = w2[widx];
    }
    fw[idx] = f2bf(v);
  } else if (idx < 25 * 4096 + 6 * 64) {
    int j = idx - 25 * 4096;
    int c = j >> 6, e = j & 63;
    int i = c / 3, t = c % 3;
    int rb = (t == 0) ? 0 : ((t == 1) ? 6 : 3);
    int rc = (t == 1) ? 2 : 3;
    float s = 0.f;
    for (int r = 0; r < rc; ++r) s += bl[(i * 8 + rb + r) * 64 + e];
    bls[c * 64 + e] = s;
  }
}

// ---------------- batched MFMA GEMM: C[n,64](bf16) = A[n,64](bf16) @ W (+bias) ----
struct GJob { const ushort* A; const ushort* W; const float* bias; ushort* C; int n; };
struct GJobs { GJob j0, j1, j2, j3; };

__global__ __launch_bounds__(256) void gemm_multi_kernel(GJobs js) {
  GJob jb = (blockIdx.y == 0) ? js.j0
          : (blockIdx.y == 1) ? js.j1
          : (blockIdx.y == 2) ? js.j2 : js.j3;
  const int n = jb.n;
  const int lane = threadIdx.x & 63;
  const int wid = (blockIdx.x * blockDim.x + threadIdx.x) >> 6;
  const int r0 = wid * 32;
  if (r0 >= n) return;
  bf8_t bw[8];
#pragma unroll
  for (int i = 0; i < 8; ++i)
    bw[i] = *(const bf8_t*)(jb.W + ((i << 6) + lane) * 8);
  const int koff = ((lane >> 4) << 3);
  int ra = r0 + (lane & 15);
  int rb = ra + 16;
  ra = min(ra, n - 1);
  rb = min(rb, n - 1);
  const bf8_t a00 = *(const bf8_t*)(jb.A + (size_t)ra * 64 + koff);
  const bf8_t a01 = *(const bf8_t*)(jb.A + (size_t)ra * 64 + 32 + koff);
  const bf8_t a10 = *(const bf8_t*)(jb.A + (size_t)rb * 64 + koff);
  const bf8_t a11 = *(const bf8_t*)(jb.A + (size_t)rb * 64 + 32 + koff);
  f32x4 acc[8];
#pragma unroll
  for (int i = 0; i < 8; ++i) acc[i] = (f32x4){0.f, 0.f, 0.f, 0.f};
#pragma unroll
  for (int ct = 0; ct < 4; ++ct) {
    acc[ct]     = __builtin_amdgcn_mfma_f32_16x16x32_bf16(a00, bw[ct * 2 + 0], acc[ct], 0, 0, 0);
    acc[ct]     = __builtin_amdgcn_mfma_f32_16x16x32_bf16(a01, bw[ct * 2 + 1], acc[ct], 0, 0, 0);
    acc[4 + ct] = __builtin_amdgcn_mfma_f32_16x16x32_bf16(a10, bw[ct * 2 + 0], acc[4 + ct], 0, 0, 0);
    acc[4 + ct] = __builtin_amdgcn_mfma_f32_16x16x32_bf16(a11, bw[ct * 2 + 1], acc[4 + ct], 0, 0, 0);
  }
  float bv[4] = {0.f, 0.f, 0.f, 0.f};
  if (jb.bias) {
#pragma unroll
    for (int ct = 0; ct < 4; ++ct) bv[ct] = jb.bias[ct * 16 + (lane & 15)];
  }
  const int rowb = r0 + ((lane >> 4) << 2);
  const int cb = lane & 15;
#pragma unroll
  for (int rt = 0; rt < 2; ++rt) {
#pragma unroll
    for (int q = 0; q < 4; ++q) {
      int row = rowb + rt * 16 + q;
      if (row < n) {
#pragma unroll
        for (int ct = 0; ct < 4; ++ct)
          jb.C[(size_t)row * 64 + ct * 16 + cb] = f2bf(acc[rt * 4 + ct][q] + bv[ct]);
      }
    }
  }
}

// ---------------- mlp stage 1: h1 = relu(x@w1+b1) -> bf16 --------------------
template <int FIN>
__global__ __launch_bounds__(256) void mlp1_kernel(
    const float* __restrict__ x, const float* __restrict__ w1,
    const float* __restrict__ b1, ushort* __restrict__ h1, int n) {
  const int lane = threadIdx.x & 63;
  int wid = (blockIdx.x * blockDim.x + threadIdx.x) >> 6;
  const int nw = (gridDim.x * blockDim.x) >> 6;
  float w1c[FIN];
#pragma unroll
  for (int k = 0; k < FIN; ++k) w1c[k] = w1[k * 64 + lane];
  const float b1v = b1[lane];
  for (int r = wid; r < n; r += nw) {
    float s = b1v;
#pragma unroll
    for (int k = 0; k < FIN; ++k) s = fmaf(x[(size_t)r * FIN + k], w1c[k], s);
    h1[(size_t)r * 64 + lane] = f2bf(fmaxf(s, 0.f));
  }
}

// ---------------- CSR build (merged over 8 relations) ------------------------
struct EIPack {
  const int* e0; const int* e1; const int* e2; const int* e3;
  const int* e4; const int* e5; const int* e6; const int* e7;
  int b0, b1, b2, b3, b4, b5, b6, b7;
};

__device__ __forceinline__ void ei_sel(const EIPack& t, int r, const int*& ei, int& b) {
  switch (r) {
    case 0: ei = t.e0; b = t.b0; break;
    case 1: ei = t.e1; b = t.b1; break;
    case 2: ei = t.e2; b = t.b2; break;
    case 3: ei = t.e3; b = t.b3; break;
    case 4: ei = t.e4; b = t.b4; break;
    case 5: ei = t.e5; b = t.b5; break;
    case 6: ei = t.e6; b = t.b6; break;
    default: ei = t.e7; b = t.b7; break;
  }
}

__global__ __launch_bounds__(256) void count8_kernel(EIPack t, int* __restrict__ cur,
                                                     int E, int cblk) {
  int r = blockIdx.x / cblk;
  int e = (blockIdx.x - r * cblk) * 256 + threadIdx.x;
  if (e >= E) return;
  const int* ei; int b;
  ei_sel(t, r, ei, b);
  atomicAdd(cur + b + ei[E + e], 1);
}

// cur holds running positions (pre-initialized to off by scan3)
__global__ __launch_bounds__(256) void fill8_kernel(EIPack t, int* __restrict__ cur,
                                                    int* __restrict__ srcs, int E, int cblk) {
  int r = blockIdx.x / cblk;
  int e = (blockIdx.x - r * cblk) * 256 + threadIdx.x;
  if (e >= E) return;
  const int* ei; int b;
  ei_sel(t, r, ei, b);
  int s = ei[e], d = ei[E + e];
  int p = atomicAdd(cur + b + d, 1);
  srcs[p] = s;
}

__global__ __launch_bounds__(256) void scan1_kernel(const int* __restrict__ cnt,
                                                    int* __restrict__ part, int n) {
  __shared__ int wt[4];
  int base = blockIdx.x * 1024;
  int t = 0;
  for (int i = threadIdx.x; i < 1024; i += 256) {
    int idx = base + i;
    if (idx < n) t += cnt[idx];
  }
#pragma unroll
  for (int d = 32; d > 0; d >>= 1) t += __shfl_xor(t, d, 64);
  if ((threadIdx.x & 63) == 0) wt[threadIdx.x >> 6] = t;
  __syncthreads();
  if (threadIdx.x == 0) part[blockIdx.x] = wt[0] + wt[1] + wt[2] + wt[3];
}

__global__ __launch_bounds__(1024) void scan2_kernel(int* __restrict__ part,
                                                     int* __restrict__ off, int nb,
                                                     int n, int total) {
  __shared__ int lds[1024];
  int tid = threadIdx.x;
  int v = (tid < nb) ? part[tid] : 0;
  lds[tid] = v;
  __syncthreads();
  for (int d = 1; d < 1024; d <<= 1) {
    int y = (tid >= d) ? lds[tid - d] : 0;
    __syncthreads();
    lds[tid] += y;
    __syncthreads();
  }
  if (tid < nb) part[tid] = lds[tid] - v;  // exclusive
  if (tid == 0) off[n] = total;
}

// writes off AND cur (= off copy used as running fill positions); cnt may alias cur
__global__ __launch_bounds__(256) void scan3_kernel(const int* cnt,
                                                    const int* __restrict__ part,
                                                    int* __restrict__ off, int* cur,
                                                    int n) {
  __shared__ int wt[4];
  int base = blockIdx.x * 1024 + threadIdx.x * 4;
  int c[4];
#pragma unroll
  for (int k = 0; k < 4; ++k) {
    int idx = base + k;
    c[k] = (idx < n) ? cnt[idx] : 0;
  }
  int t = c[0] + c[1] + c[2] + c[3];
  int lane = threadIdx.x & 63, w = threadIdx.x >> 6;
  int x = t;
#pragma unroll
  for (int d = 1; d < 64; d <<= 1) {
    int y = __shfl_up(x, d, 64);
    if (lane >= d) x += y;
  }
  int ex = x - t;
  if (lane == 63) wt[w] = x;
  __syncthreads();
  int woff = 0;
#pragma unroll
  for (int k = 0; k < 4; ++k)
    if (k < w) woff += wt[k];
  int pos = part[blockIdx.x] + woff + ex;
#pragma unroll
  for (int k = 0; k < 4; ++k) {
    int idx = base + k;
    if (idx < n) { off[idx] = pos; cur[idx] = pos; }
    pos += c[k];
  }
}

// ---- fused gather+final: h_new = LN(h_old + relu(sum_r mean_r + t + bls)) ----
// one dst row per 8-lane group; lane l8 owns columns [l8*8, l8*8+8).
__device__ __forceinline__ void gather_rel(const ushort* __restrict__ g,
    const int* __restrict__ srcs, const int* __restrict__ off, int bofs, int d,
    int l8, float o[8]) {
  int e0 = off[bofs + d], e1 = off[bofs + d + 1];
  float t8[8];
#pragma unroll
  for (int c = 0; c < 8; ++c) t8[c] = 0.f;
  for (int j = e0; j < e1; ++j) {
    int s = srcs[j];
    bf8_t v = *(const bf8_t*)(g + (size_t)s * 64 + l8 * 8);
#pragma unroll
    for (int c = 0; c < 8; ++c) t8[c] += u2f((ushort)v[c]);
  }
  float inv = 1.f / fmaxf((float)(e1 - e0), 1.f);
#pragma unroll
  for (int c = 0; c < 8; ++c) o[c] = fmaf(t8[c], inv, o[c]);
}

__global__ __launch_bounds__(256) void gf_kernel(
    const ushort* __restrict__ g0, const ushort* __restrict__ g1,
    const ushort* __restrict__ g2, const int* __restrict__ srcs,
    const int* __restrict__ off, int b0_, int b1_, int b2_, int nrel,
    const ushort* __restrict__ t, const ushort* __restrict__ hold,
    ushort* __restrict__ hnew, const float* __restrict__ bls,
    const float* __restrict__ lng, const float* __restrict__ lnb, int ndst) {
  const int l8 = threadIdx.x & 7;
  const int d = (blockIdx.x * blockDim.x + threadIdx.x) >> 3;
  if (d >= ndst) return;
  float blr[8], ggr[8], bbr[8];
  *(float4*)(blr)     = *(const float4*)(bls + l8 * 8);
  *(float4*)(blr + 4) = *(const float4*)(bls + l8 * 8 + 4);
  *(float4*)(ggr)     = *(const float4*)(lng + l8 * 8);
  *(float4*)(ggr + 4) = *(const float4*)(lng + l8 * 8 + 4);
  *(float4*)(bbr)     = *(const float4*)(lnb + l8 * 8);
  *(float4*)(bbr + 4) = *(const float4*)(lnb + l8 * 8 + 4);
  float o[8];
#pragma unroll
  for (int c = 0; c < 8; ++c) o[c] = 0.f;
  gather_rel(g0, srcs, off, b0_, d, l8, o);
  if (nrel > 1) gather_rel(g1, srcs, off, b1_, d, l8, o);
  if (nrel > 2) gather_rel(g2, srcs, off, b2_, d, l8, o);
  bf8_t tv = *(const bf8_t*)(t + (size_t)d * 64 + l8 * 8);
  bf8_t hv = *(const bf8_t*)(hold + (size_t)d * 64 + l8 * 8);
  float v[8];
  float s = 0.f;
#pragma unroll
  for (int c = 0; c < 8; ++c) {
    float x = u2f((ushort)hv[c]) + fmaxf(o[c] + u2f((ushort)tv[c]) + blr[c], 0.f);
    v[c] = x;
    s += x;
  }
  s += __shfl_xor(s, 1, 64);
  s += __shfl_xor(s, 2, 64);
  s += __shfl_xor(s, 4, 64);
  float m = s * (1.f / 64.f);
  float vs = 0.f;
#pragma unroll
  for (int c = 0; c < 8; ++c) {
    float dd = v[c] - m;
    vs += dd * dd;
  }
  vs += __shfl_xor(vs, 1, 64);
  vs += __shfl_xor(vs, 2, 64);
  vs += __shfl_xor(vs, 4, 64);
  float rstd = rsqrtf(vs * (1.f / 64.f) + 1e-5f);
  bf8_t outv;
#pragma unroll
  for (int c = 0; c < 8; ++c)
    outv[c] = (short)f2bf((v[c] - m) * rstd * ggr[c] + bbr[c]);
  *(bf8_t*)(hnew + (size_t)d * 64 + l8 * 8) = outv;
}

// ---------------- pool (all 3 types in one dispatch via y) -------------------
struct PoolArgs {
  const ushort* h0; const ushort* h1; const ushort* h2;
  const int* b0; const int* b1; const int* b2;
  int n0, n1, n2;
};

__global__ __launch_bounds__(64) void pool_kernel(PoolArgs a, float* __restrict__ out) {
  int ty = blockIdx.y;
  const ushort* h = (ty == 0) ? a.h0 : (ty == 1) ? a.h1 : a.h2;
  const int* batch = (ty == 0) ? a.b0 : (ty == 1) ? a.b1 : a.b2;
  int n = (ty == 0) ? a.n0 : (ty == 1) ? a.n1 : a.n2;
  int col_base = ty * 64;
  const int lane = threadIdx.x;
  int gph = blockIdx.x >> 4;
  int s = blockIdx.x & 15;
  int lo = 0, hi = n;
  while (lo < hi) { int mid = (lo + hi) >> 1; if (batch[mid] < gph) lo = mid + 1; else hi = mid; }
  int beg = lo;
  hi = n;
  while (lo < hi) { int mid = (lo + hi) >> 1; if (batch[mid] < gph + 1) lo = mid + 1; else hi = mid; }
  int end = lo;
  int cnt = end - beg;
  if (cnt <= 0) return;
  int per = (cnt + POOL_SPLIT - 1) >> 4;
  int rb = beg + s * per;
  int re = min(rb + per, end);
  if (rb >= re) return;
  float acc = 0.f;
  for (int r = rb; r < re; ++r) acc += u2f(h[(size_t)r * 64 + lane]);
  unsafeAtomicAdd(out + gph * 192 + col_base + lane, acc);
}

__global__ __launch_bounds__(256) void pool_scale_kernel(
    float* __restrict__ out, const int* __restrict__ bp,
    const int* __restrict__ be, const int* __restrict__ bf,
    int np, int ne, int nf) {
  int idx = blockIdx.x * blockDim.x + threadIdx.x;
  if (idx >= 64 * 192) return;
  int gph = idx / 192, col = idx % 192;
  const int* b;
  int n;
  if (col < 64) { b = bp; n = np; }
  else if (col < 128) { b = be; n = ne; }
  else { b = bf; n = nf; }
  int lo = 0, hi = n;
  while (lo < hi) { int mid = (lo + hi) >> 1; if (b[mid] < gph) lo = mid + 1; else hi = mid; }
  int beg = lo;
  hi = n;
  while (lo < hi) { int mid = (lo + hi) >> 1; if (b[mid] < gph + 1) lo = mid + 1; else hi = mid; }
  int cnt = lo - beg;
  out[idx] = out[idx] / fmaxf((float)cnt, 1.f);
}

extern "C" void kernel_launch(void* const* d_in, const int* in_sizes, int n_in,
                              void* d_out, int out_size, void* d_ws, size_t ws_size,
                              hipStream_t stream) {
  const float* point_x = (const float*)d_in[0];
  const float* edge_x  = (const float*)d_in[1];
  const float* face_x  = (const float*)d_in[2];
  const int* bp = (const int*)d_in[3];
  const int* be = (const int*)d_in[4];
  const int* bf = (const int*)d_in[5];
  const int NP = in_sizes[3], NE = in_sizes[4], NF = in_sizes[5];
  const int Eg = in_sizes[6] / 2;

  const float* Wl  = (const float*)d_in[26];
  const float* blp = (const float*)d_in[27];
  const float* Wr  = (const float*)d_in[28];
  const float* lng = (const float*)d_in[29];
  const float* lnb = (const float*)d_in[30];

  // ---- workspace layout ----
  char* p = (char*)d_ws;
  ushort* hA = (ushort*)p; p += (size_t)(NP + NE + NF) * 64 * 2;
  ushort* hB = (ushort*)p; p += (size_t)(NP + NE + NF) * 64 * 2;
  ushort* g  = (ushort*)p; p += (size_t)(NP + NE + NE) * 64 * 2;
  ushort* tb = (ushort*)p; p += (size_t)NP * 64 * 2;
  ushort* fw = (ushort*)p; p += (size_t)25 * 4096 * 2;
  float* bls = (float*)p; p += 6 * 64 * 4;
  int* srcs = (int*)p; p += (size_t)8 * Eg * 4;
  const int NDSUM = 3 * NP + 3 * NF + 2 * NE;
  int* off = (int*)p; p += (size_t)(NDSUM + 1) * 4;
  int* cur = (int*)p; p += (size_t)NDSUM * 4;
  int* part = (int*)p; p += 4096;

  ushort* hptr[2][3];  // [set][type 0=p,1=e,2=f]
  hptr[0][0] = hA; hptr[0][1] = hA + (size_t)NP * 64; hptr[0][2] = hA + (size_t)(NP + NE) * 64;
  hptr[1][0] = hB; hptr[1][1] = hB + (size_t)NP * 64; hptr[1][2] = hB + (size_t)(NP + NE) * 64;
  ushort* gs[3] = {g, g + (size_t)NP * 64, g + (size_t)(NP + NE) * 64};

  // relations: 0 pp 1 fp 2 ep (dst P) | 3 pf 4 ef 5 ff (dst F) | 6 pe 7 fe (dst E)
  const int* ei[8] = {(const int*)d_in[6],  (const int*)d_in[7],
                      (const int*)d_in[8],  (const int*)d_in[9],
                      (const int*)d_in[10], (const int*)d_in[11],
                      (const int*)d_in[12], (const int*)d_in[13]};
  int ndst[8] = {NP, NP, NP, NF, NF, NF, NE, NE};
  int base[8];
  base[0] = 0;
  for (int r = 1; r < 8; ++r) base[r] = base[r - 1] + ndst[r - 1];

  EIPack ep;
  ep.e0 = ei[0]; ep.e1 = ei[1]; ep.e2 = ei[2]; ep.e3 = ei[3];
  ep.e4 = ei[4]; ep.e5 = ei[5]; ep.e6 = ei[6]; ep.e7 = ei[7];
  ep.b0 = base[0]; ep.b1 = base[1]; ep.b2 = base[2]; ep.b3 = base[3];
  ep.b4 = base[4]; ep.b5 = base[5]; ep.b6 = base[6]; ep.b7 = base[7];

  // ---- CSR build (edge indices shared by both layers) ----
  const int cblk = (Eg + 255) / 256;
  hipMemsetAsync(cur, 0, (size_t)NDSUM * 4, stream);
  count8_kernel<<<8 * cblk, 256, 0, stream>>>(ep, cur, Eg, cblk);
  const int nb = (NDSUM + 1023) / 1024;
  scan1_kernel<<<nb, 256, 0, stream>>>(cur, part, NDSUM);
  scan2_kernel<<<1, 1024, 0, stream>>>(part, off, nb, NDSUM, 8 * Eg);
  scan3_kernel<<<nb, 256, 0, stream>>>(cur, part, off, cur, NDSUM);
  fill8_kernel<<<8 * cblk, 256, 0, stream>>>(ep, cur, srcs, Eg, cblk);

  // ---- weight prep ----
  prep_kernel<<<(25 * 4096 + 6 * 64 + 255) / 256, 256, 0, stream>>>(
      Wl, Wr, blp, (const float*)d_in[16], (const float*)d_in[20],
      (const float*)d_in[24], fw, bls);

  auto gblk = [](int n) { return ((n + 31) / 32 + 3) / 4; };
  auto launch_gemm = [&](GJob a, GJob b, GJob c, GJob d, int cnt) {
    GJobs js;
    js.j0 = a; js.j1 = b; js.j2 = c; js.j3 = d;
    int mx = gblk(a.n);
    mx = max(mx, gblk(b.n));
    if (cnt > 2) mx = max(mx, gblk(c.n));
    if (cnt > 3) mx = max(mx, gblk(d.n));
    gemm_multi_kernel<<<dim3(mx, cnt), 256, 0, stream>>>(js);
  };

  // ---- input MLPs (stage1 VALU -> staging, stage2 batched MFMA -> hA) ----
  mlp1_kernel<3><<<1024, 256, 0, stream>>>(point_x, (const float*)d_in[14],
      (const float*)d_in[15], gs[0], NP);
  mlp1_kernel<2><<<1024, 256, 0, stream>>>(edge_x, (const float*)d_in[18],
      (const float*)d_in[19], gs[1], NE);
  mlp1_kernel<16><<<1024, 256, 0, stream>>>(face_x, (const float*)d_in[22],
      (const float*)d_in[23], gs[2], NF);
  launch_gemm({gs[0], fw + 22 * 4096, (const float*)d_in[17], hptr[0][0], NP},
              {gs[1], fw + 23 * 4096, (const float*)d_in[21], hptr[0][1], NE},
              {gs[2], fw + 24 * 4096, (const float*)d_in[25], hptr[0][2], NF},
              {gs[2], fw + 24 * 4096, nullptr, hptr[0][2], 0}, 3);

  auto gfblk = [](int n) { return (n * 8 + 255) / 256; };

  // ---- 2 hetero-SAGE layers (read set cs, write set ns) ----
  int cs = 0;
  for (int i = 0; i < 2; ++i) {
    int ns = cs ^ 1;
    ushort* hp_ = hptr[cs][0];
    ushort* he_ = hptr[cs][1];
    ushort* hf_ = hptr[cs][2];
    // point phase: rels 0(src p),1(src f),2(src e) + t = hp@Wrs
    launch_gemm({hp_, fw + (size_t)(i * 8 + 0) * 4096, nullptr, gs[0], NP},
                {hf_, fw + (size_t)(i * 8 + 1) * 4096, nullptr, gs[1], NF},
                {he_, fw + (size_t)(i * 8 + 2) * 4096, nullptr, gs[2], NE},
                {hp_, fw + (size_t)(16 + i * 3 + 0) * 4096, nullptr, tb, NP}, 4);
    gf_kernel<<<gfblk(NP), 256, 0, stream>>>(gs[0], gs[1], gs[2], srcs, off,
        base[0], base[1], base[2], 3, tb, hp_, hptr[ns][0],
        bls + (i * 3 + 0) * 64, lng + (i * 3 + 0) * 64, lnb + (i * 3 + 0) * 64, NP);
    // face phase: rels 3(src p),4(src e),5(src f) + t = hf@Wrs
    launch_gemm({hp_, fw + (size_t)(i * 8 + 3) * 4096, nullptr, gs[0], NP},
                {he_, fw + (size_t)(i * 8 + 4) * 4096, nullptr, gs[1], NE},
                {hf_, fw + (size_t)(i * 8 + 5) * 4096, nullptr, gs[2], NF},
                {hf_, fw + (size_t)(16 + i * 3 + 2) * 4096, nullptr, tb, NF}, 4);
    gf_kernel<<<gfblk(NF), 256, 0, stream>>>(gs[0], gs[1], gs[2], srcs, off,
        base[3], base[4], base[5], 3, tb, hf_, hptr[ns][2],
        bls + (i * 3 + 2) * 64, lng + (i * 3 + 2) * 64, lnb + (i * 3 + 2) * 64, NF);
    // edge phase: rels 6(src p),7(src f) + t = he@Wrs
    launch_gemm({hp_, fw + (size_t)(i * 8 + 6) * 4096, nullptr, gs[0], NP},
                {hf_, fw + (size_t)(i * 8 + 7) * 4096, nullptr, gs[1], NF},
                {he_, fw + (size_t)(16 + i * 3 + 1) * 4096, nullptr, tb, NE},
                {he_, fw + (size_t)(16 + i * 3 + 1) * 4096, nullptr, tb, 0}, 3);
    gf_kernel<<<gfblk(NE), 256, 0, stream>>>(gs[0], gs[1], nullptr, srcs, off,
        base[6], base[7], 0, 2, tb, he_, hptr[ns][1],
        bls + (i * 3 + 1) * 64, lng + (i * 3 + 1) * 64, lnb + (i * 3 + 1) * 64, NE);
    cs = ns;
  }

  // ---- pool + scale ----
  float* out = (float*)d_out;
  hipMemsetAsync(out, 0, (size_t)out_size * sizeof(float), stream);
  PoolArgs pa;
  pa.h0 = hptr[cs][0]; pa.h1 = hptr[cs][1]; pa.h2 = hptr[cs][2];
  pa.b0 = bp; pa.b1 = be; pa.b2 = bf;
  pa.n0 = NP; pa.n1 = NE; pa.n2 = NF;
  pool_kernel<<<dim3(64 * POOL_SPLIT, 3), 64, 0, stream>>>(pa, out);
  pool_scale_kernel<<<(64 * 192 + 255) / 256, 256, 0, stream>>>(out, bp, be, bf, NP, NE, NF);
}

// Round 6
// 980.328 us; speedup vs baseline: 9.7338x; 1.0191x over previous
//
#include <hip/hip_runtime.h>
#include <hip/hip_bf16.h>

// CADTopoEncoder: hetero-GNN (point/edge/face), 2 SAGE layers + LN + pool.
// bf16 hidden state (double-buffered); all 64x64 matmuls via mfma_f32_16x16x32_bf16
// (batched multi-job kernel); CSR gather fused with residual+ReLU+LN.
// CSR fill is range-partitioned (4 passes) so scattered srcs writes stay
// L2-resident until lines are fully written (kills 16x write amplification).

#define POOL_SPLIT 16
#define FILL_PASSES 4
#define COUNT_PASSES 2

typedef __attribute__((ext_vector_type(8))) short bf8_t;   // 8 bf16 in 4 VGPRs
typedef __attribute__((ext_vector_type(4))) float f32x4;

__device__ __forceinline__ ushort f2bf(float f) {
  union { __hip_bfloat16 b; ushort u; } v;
  v.b = __float2bfloat16(f);
  return v.u;
}
__device__ __forceinline__ float u2f(ushort u) {
  union { ushort u; __hip_bfloat16 b; } v;
  v.u = u;
  return __bfloat162float(v.b);
}

// ---------------- prep: weights -> bf16 MFMA fragment order, summed biases ----
// fw holds 25 matrices (4096 bf16 each): m 0..15 Wl[i*8+rel]; 16..21 Wrs per
// (layer,type); 22..24 mlp w2 p/e/f.
__global__ __launch_bounds__(256) void prep_kernel(
    const float* __restrict__ Wl, const float* __restrict__ Wr,
    const float* __restrict__ bl, const float* __restrict__ w2p,
    const float* __restrict__ w2e, const float* __restrict__ w2f,
    ushort* __restrict__ fw, float* __restrict__ bls) {
  int idx = blockIdx.x * blockDim.x + threadIdx.x;
  if (idx < 25 * 4096) {
    int m = idx >> 12, e = idx & 4095;
    int i8 = e >> 3, b = e & 7;
    int lane = i8 & 63, cb = i8 >> 6;
    int ks = cb & 1, ct = cb >> 1;
    int k = ks * 32 + ((lane >> 4) << 3) + b;
    int col = (ct << 4) + (lane & 15);
    int widx = (k << 6) + col;
    float v;
    if (m < 16) {
      v = Wl[(size_t)m * 4096 + widx];
    } else if (m < 22) {
      int c = m - 16, i = c / 3, t = c % 3;
      int rb = (t == 0) ? 0 : ((t == 1) ? 6 : 3);
      int rc = (t == 1) ? 2 : 3;
      v = 0.f;
      for (int r = 0; r < rc; ++r) v += Wr[(size_t)(i * 8 + rb + r) * 4096 + widx];
    } else {
      const float* w2 = (m == 22) ? w2p : ((m == 23) ? w2e : w2f);
      v = w2[widx];
    }
    fw[idx] = f2bf(v);
  } else if (idx < 25 * 4096 + 6 * 64) {
    int j = idx - 25 * 4096;
    int c = j >> 6, e = j & 63;
    int i = c / 3, t = c % 3;
    int rb = (t == 0) ? 0 : ((t == 1) ? 6 : 3);
    int rc = (t == 1) ? 2 : 3;
    float s = 0.f;
    for (int r = 0; r < rc; ++r) s += bl[(i * 8 + rb + r) * 64 + e];
    bls[c * 64 + e] = s;
  }
}

// ---------------- batched MFMA GEMM: C[n,64](bf16) = A[n,64](bf16) @ W (+bias) ----
struct GJob { const ushort* A; const ushort* W; const float* bias; ushort* C; int n; };
struct GJobs { GJob j0, j1, j2, j3; };

__global__ __launch_bounds__(256) void gemm_multi_kernel(GJobs js) {
  GJob jb = (blockIdx.y == 0) ? js.j0
          : (blockIdx.y == 1) ? js.j1
          : (blockIdx.y == 2) ? js.j2 : js.j3;
  const int n = jb.n;
  const int lane = threadIdx.x & 63;
  const int wid = (blockIdx.x * blockDim.x + threadIdx.x) >> 6;
  const int r0 = wid * 32;
  if (r0 >= n) return;
  bf8_t bw[8];
#pragma unroll
  for (int i = 0; i < 8; ++i)
    bw[i] = *(const bf8_t*)(jb.W + ((i << 6) + lane) * 8);
  const int koff = ((lane >> 4) << 3);
  int ra = r0 + (lane & 15);
  int rb = ra + 16;
  ra = min(ra, n - 1);
  rb = min(rb, n - 1);
  const bf8_t a00 = *(const bf8_t*)(jb.A + (size_t)ra * 64 + koff);
  const bf8_t a01 = *(const bf8_t*)(jb.A + (size_t)ra * 64 + 32 + koff);
  const bf8_t a10 = *(const bf8_t*)(jb.A + (size_t)rb * 64 + koff);
  const bf8_t a11 = *(const bf8_t*)(jb.A + (size_t)rb * 64 + 32 + koff);
  f32x4 acc[8];
#pragma unroll
  for (int i = 0; i < 8; ++i) acc[i] = (f32x4){0.f, 0.f, 0.f, 0.f};
#pragma unroll
  for (int ct = 0; ct < 4; ++ct) {
    acc[ct]     = __builtin_amdgcn_mfma_f32_16x16x32_bf16(a00, bw[ct * 2 + 0], acc[ct], 0, 0, 0);
    acc[ct]     = __builtin_amdgcn_mfma_f32_16x16x32_bf16(a01, bw[ct * 2 + 1], acc[ct], 0, 0, 0);
    acc[4 + ct] = __builtin_amdgcn_mfma_f32_16x16x32_bf16(a10, bw[ct * 2 + 0], acc[4 + ct], 0, 0, 0);
    acc[4 + ct] = __builtin_amdgcn_mfma_f32_16x16x32_bf16(a11, bw[ct * 2 + 1], acc[4 + ct], 0, 0, 0);
  }
  float bv[4] = {0.f, 0.f, 0.f, 0.f};
  if (jb.bias) {
#pragma unroll
    for (int ct = 0; ct < 4; ++ct) bv[ct] = jb.bias[ct * 16 + (lane & 15)];
  }
  const int rowb = r0 + ((lane >> 4) << 2);
  const int cb = lane & 15;
#pragma unroll
  for (int rt = 0; rt < 2; ++rt) {
#pragma unroll
    for (int q = 0; q < 4; ++q) {
      int row = rowb + rt * 16 + q;
      if (row < n) {
#pragma unroll
        for (int ct = 0; ct < 4; ++ct)
          jb.C[(size_t)row * 64 + ct * 16 + cb] = f2bf(acc[rt * 4 + ct][q] + bv[ct]);
      }
    }
  }
}

// ---------------- mlp stage 1: h1 = relu(x@w1+b1) -> bf16 --------------------
template <int FIN>
__global__ __launch_bounds__(256) void mlp1_kernel(
    const float* __restrict__ x, const float* __restrict__ w1,
    const float* __restrict__ b1, ushort* __restrict__ h1, int n) {
  const int lane = threadIdx.x & 63;
  int wid = (blockIdx.x * blockDim.x + threadIdx.x) >> 6;
  const int nw = (gridDim.x * blockDim.x) >> 6;
  float w1c[FIN];
#pragma unroll
  for (int k = 0; k < FIN; ++k) w1c[k] = w1[k * 64 + lane];
  const float b1v = b1[lane];
  for (int r = wid; r < n; r += nw) {
    float s = b1v;
#pragma unroll
    for (int k = 0; k < FIN; ++k) s = fmaf(x[(size_t)r * FIN + k], w1c[k], s);
    h1[(size_t)r * 64 + lane] = f2bf(fmaxf(s, 0.f));
  }
}

// ---------------- CSR build (merged over 8 relations, range-partitioned) -----
struct EIPack {
  const int* e0; const int* e1; const int* e2; const int* e3;
  const int* e4; const int* e5; const int* e6; const int* e7;
  int b0, b1, b2, b3, b4, b5, b6, b7;
};

__device__ __forceinline__ void ei_sel(const EIPack& t, int r, const int*& ei, int& b) {
  switch (r) {
    case 0: ei = t.e0; b = t.b0; break;
    case 1: ei = t.e1; b = t.b1; break;
    case 2: ei = t.e2; b = t.b2; break;
    case 3: ei = t.e3; b = t.b3; break;
    case 4: ei = t.e4; b = t.b4; break;
    case 5: ei = t.e5; b = t.b5; break;
    case 6: ei = t.e6; b = t.b6; break;
    default: ei = t.e7; b = t.b7; break;
  }
}

// only count dsts whose global counter index falls in [c0, c1)
__global__ __launch_bounds__(256) void count8_kernel(EIPack t, int* __restrict__ cur,
                                                     int E, int cblk, int c0, int c1) {
  int r = blockIdx.x / cblk;
  int e = (blockIdx.x - r * cblk) * 256 + threadIdx.x;
  if (e >= E) return;
  const int* ei; int b;
  ei_sel(t, r, ei, b);
  int g = b + ei[E + e];
  if (g < c0 || g >= c1) return;
  atomicAdd(cur + g, 1);
}

// cur holds running positions (pre-initialized to off by scan3);
// only fill edges whose global counter index falls in [c0, c1) -> srcs writes
// land in a contiguous ~(total/FILL_PASSES) region that stays L2-resident.
__global__ __launch_bounds__(256) void fill8_kernel(EIPack t, int* __restrict__ cur,
                                                    int* __restrict__ srcs, int E,
                                                    int cblk, int c0, int c1) {
  int r = blockIdx.x / cblk;
  int e = (blockIdx.x - r * cblk) * 256 + threadIdx.x;
  if (e >= E) return;
  const int* ei; int b;
  ei_sel(t, r, ei, b);
  int g = b + ei[E + e];
  if (g < c0 || g >= c1) return;
  int s = ei[e];
  int p = atomicAdd(cur + g, 1);
  srcs[p] = s;
}

__global__ __launch_bounds__(256) void scan1_kernel(const int* __restrict__ cnt,
                                                    int* __restrict__ part, int n) {
  __shared__ int wt[4];
  int base = blockIdx.x * 1024;
  int t = 0;
  for (int i = threadIdx.x; i < 1024; i += 256) {
    int idx = base + i;
    if (idx < n) t += cnt[idx];
  }
#pragma unroll
  for (int d = 32; d > 0; d >>= 1) t += __shfl_xor(t, d, 64);
  if ((threadIdx.x & 63) == 0) wt[threadIdx.x >> 6] = t;
  __syncthreads();
  if (threadIdx.x == 0) part[blockIdx.x] = wt[0] + wt[1] + wt[2] + wt[3];
}

__global__ __launch_bounds__(1024) void scan2_kernel(int* __restrict__ part,
                                                     int* __restrict__ off, int nb,
                                                     int n, int total) {
  __shared__ int lds[1024];
  int tid = threadIdx.x;
  int v = (tid < nb) ? part[tid] : 0;
  lds[tid] = v;
  __syncthreads();
  for (int d = 1; d < 1024; d <<= 1) {
    int y = (tid >= d) ? lds[tid - d] : 0;
    __syncthreads();
    lds[tid] += y;
    __syncthreads();
  }
  if (tid < nb) part[tid] = lds[tid] - v;  // exclusive
  if (tid == 0) off[n] = total;
}

// writes off AND cur (= off copy used as running fill positions); cnt may alias cur
__global__ __launch_bounds__(256) void scan3_kernel(const int* cnt,
                                                    const int* __restrict__ part,
                                                    int* __restrict__ off, int* cur,
                                                    int n) {
  __shared__ int wt[4];
  int base = blockIdx.x * 1024 + threadIdx.x * 4;
  int c[4];
#pragma unroll
  for (int k = 0; k < 4; ++k) {
    int idx = base + k;
    c[k] = (idx < n) ? cnt[idx] : 0;
  }
  int t = c[0] + c[1] + c[2] + c[3];
  int lane = threadIdx.x & 63, w = threadIdx.x >> 6;
  int x = t;
#pragma unroll
  for (int d = 1; d < 64; d <<= 1) {
    int y = __shfl_up(x, d, 64);
    if (lane >= d) x += y;
  }
  int ex = x - t;
  if (lane == 63) wt[w] = x;
  __syncthreads();
  int woff = 0;
#pragma unroll
  for (int k = 0; k < 4; ++k)
    if (k < w) woff += wt[k];
  int pos = part[blockIdx.x] + woff + ex;
#pragma unroll
  for (int k = 0; k < 4; ++k) {
    int idx = base + k;
    if (idx < n) { off[idx] = pos; cur[idx] = pos; }
    pos += c[k];
  }
}

// ---- fused gather+final: h_new = LN(h_old + relu(sum_r mean_r + t + bls)) ----
// one dst row per 8-lane group; lane l8 owns columns [l8*8, l8*8+8).
__device__ __forceinline__ void gather_rel(const ushort* __restrict__ g,
    const int* __restrict__ srcs, const int* __restrict__ off, int bofs, int d,
    int l8, float o[8]) {
  int e0 = off[bofs + d], e1 = off[bofs + d + 1];
  float t8[8];
#pragma unroll
  for (int c = 0; c < 8; ++c) t8[c] = 0.f;
  for (int j = e0; j < e1; ++j) {
    int s = srcs[j];
    bf8_t v = *(const bf8_t*)(g + (size_t)s * 64 + l8 * 8);
#pragma unroll
    for (int c = 0; c < 8; ++c) t8[c] += u2f((ushort)v[c]);
  }
  float inv = 1.f / fmaxf((float)(e1 - e0), 1.f);
#pragma unroll
  for (int c = 0; c < 8; ++c) o[c] = fmaf(t8[c], inv, o[c]);
}

__global__ __launch_bounds__(256) void gf_kernel(
    const ushort* __restrict__ g0, const ushort* __restrict__ g1,
    const ushort* __restrict__ g2, const int* __restrict__ srcs,
    const int* __restrict__ off, int b0_, int b1_, int b2_, int nrel,
    const ushort* __restrict__ t, const ushort* __restrict__ hold,
    ushort* __restrict__ hnew, const float* __restrict__ bls,
    const float* __restrict__ lng, const float* __restrict__ lnb, int ndst) {
  const int l8 = threadIdx.x & 7;
  const int d = (blockIdx.x * blockDim.x + threadIdx.x) >> 3;
  if (d >= ndst) return;
  float blr[8], ggr[8], bbr[8];
  *(float4*)(blr)     = *(const float4*)(bls + l8 * 8);
  *(float4*)(blr + 4) = *(const float4*)(bls + l8 * 8 + 4);
  *(float4*)(ggr)     = *(const float4*)(lng + l8 * 8);
  *(float4*)(ggr + 4) = *(const float4*)(lng + l8 * 8 + 4);
  *(float4*)(bbr)     = *(const float4*)(lnb + l8 * 8);
  *(float4*)(bbr + 4) = *(const float4*)(lnb + l8 * 8 + 4);
  float o[8];
#pragma unroll
  for (int c = 0; c < 8; ++c) o[c] = 0.f;
  gather_rel(g0, srcs, off, b0_, d, l8, o);
  if (nrel > 1) gather_rel(g1, srcs, off, b1_, d, l8, o);
  if (nrel > 2) gather_rel(g2, srcs, off, b2_, d, l8, o);
  bf8_t tv = *(const bf8_t*)(t + (size_t)d * 64 + l8 * 8);
  bf8_t hv = *(const bf8_t*)(hold + (size_t)d * 64 + l8 * 8);
  float v[8];
  float s = 0.f;
#pragma unroll
  for (int c = 0; c < 8; ++c) {
    float x = u2f((ushort)hv[c]) + fmaxf(o[c] + u2f((ushort)tv[c]) + blr[c], 0.f);
    v[c] = x;
    s += x;
  }
  s += __shfl_xor(s, 1, 64);
  s += __shfl_xor(s, 2, 64);
  s += __shfl_xor(s, 4, 64);
  float m = s * (1.f / 64.f);
  float vs = 0.f;
#pragma unroll
  for (int c = 0; c < 8; ++c) {
    float dd = v[c] - m;
    vs += dd * dd;
  }
  vs += __shfl_xor(vs, 1, 64);
  vs += __shfl_xor(vs, 2, 64);
  vs += __shfl_xor(vs, 4, 64);
  float rstd = rsqrtf(vs * (1.f / 64.f) + 1e-5f);
  bf8_t outv;
#pragma unroll
  for (int c = 0; c < 8; ++c)
    outv[c] = (short)f2bf((v[c] - m) * rstd * ggr[c] + bbr[c]);
  *(bf8_t*)(hnew + (size_t)d * 64 + l8 * 8) = outv;
}

// ---------------- pool (all 3 types in one dispatch via y) -------------------
struct PoolArgs {
  const ushort* h0; const ushort* h1; const ushort* h2;
  const int* b0; const int* b1; const int* b2;
  int n0, n1, n2;
};

__global__ __launch_bounds__(64) void pool_kernel(PoolArgs a, float* __restrict__ out) {
  int ty = blockIdx.y;
  const ushort* h = (ty == 0) ? a.h0 : (ty == 1) ? a.h1 : a.h2;
  const int* batch = (ty == 0) ? a.b0 : (ty == 1) ? a.b1 : a.b2;
  int n = (ty == 0) ? a.n0 : (ty == 1) ? a.n1 : a.n2;
  int col_base = ty * 64;
  const int lane = threadIdx.x;
  int gph = blockIdx.x >> 4;
  int s = blockIdx.x & 15;
  int lo = 0, hi = n;
  while (lo < hi) { int mid = (lo + hi) >> 1; if (batch[mid] < gph) lo = mid + 1; else hi = mid; }
  int beg = lo;
  hi = n;
  while (lo < hi) { int mid = (lo + hi) >> 1; if (batch[mid] < gph + 1) lo = mid + 1; else hi = mid; }
  int end = lo;
  int cnt = end - beg;
  if (cnt <= 0) return;
  int per = (cnt + POOL_SPLIT - 1) >> 4;
  int rb = beg + s * per;
  int re = min(rb + per, end);
  if (rb >= re) return;
  float acc = 0.f;
  for (int r = rb; r < re; ++r) acc += u2f(h[(size_t)r * 64 + lane]);
  unsafeAtomicAdd(out + gph * 192 + col_base + lane, acc);
}

__global__ __launch_bounds__(256) void pool_scale_kernel(
    float* __restrict__ out, const int* __restrict__ bp,
    const int* __restrict__ be, const int* __restrict__ bf,
    int np, int ne, int nf) {
  int idx = blockIdx.x * blockDim.x + threadIdx.x;
  if (idx >= 64 * 192) return;
  int gph = idx / 192, col = idx % 192;
  const int* b;
  int n;
  if (col < 64) { b = bp; n = np; }
  else if (col < 128) { b = be; n = ne; }
  else { b = bf; n = nf; }
  int lo = 0, hi = n;
  while (lo < hi) { int mid = (lo + hi) >> 1; if (b[mid] < gph) lo = mid + 1; else hi = mid; }
  int beg = lo;
  hi = n;
  while (lo < hi) { int mid = (lo + hi) >> 1; if (b[mid] < gph + 1) lo = mid + 1; else hi = mid; }
  int cnt = lo - beg;
  out[idx] = out[idx] / fmaxf((float)cnt, 1.f);
}

extern "C" void kernel_launch(void* const* d_in, const int* in_sizes, int n_in,
                              void* d_out, int out_size, void* d_ws, size_t ws_size,
                              hipStream_t stream) {
  const float* point_x = (const float*)d_in[0];
  const float* edge_x  = (const float*)d_in[1];
  const float* face_x  = (const float*)d_in[2];
  const int* bp = (const int*)d_in[3];
  const int* be = (const int*)d_in[4];
  const int* bf = (const int*)d_in[5];
  const int NP = in_sizes[3], NE = in_sizes[4], NF = in_sizes[5];
  const int Eg = in_sizes[6] / 2;

  const float* Wl  = (const float*)d_in[26];
  const float* blp = (const float*)d_in[27];
  const float* Wr  = (const float*)d_in[28];
  const float* lng = (const float*)d_in[29];
  const float* lnb = (const float*)d_in[30];

  // ---- workspace layout ----
  char* p = (char*)d_ws;
  ushort* hA = (ushort*)p; p += (size_t)(NP + NE + NF) * 64 * 2;
  ushort* hB = (ushort*)p; p += (size_t)(NP + NE + NF) * 64 * 2;
  ushort* g  = (ushort*)p; p += (size_t)(NP + NE + NE) * 64 * 2;
  ushort* tb = (ushort*)p; p += (size_t)NP * 64 * 2;
  ushort* fw = (ushort*)p; p += (size_t)25 * 4096 * 2;
  float* bls = (float*)p; p += 6 * 64 * 4;
  int* srcs = (int*)p; p += (size_t)8 * Eg * 4;
  const int NDSUM = 3 * NP + 3 * NF + 2 * NE;
  int* off = (int*)p; p += (size_t)(NDSUM + 1) * 4;
  int* cur = (int*)p; p += (size_t)NDSUM * 4;
  int* part = (int*)p; p += 4096;

  ushort* hptr[2][3];  // [set][type 0=p,1=e,2=f]
  hptr[0][0] = hA; hptr[0][1] = hA + (size_t)NP * 64; hptr[0][2] = hA + (size_t)(NP + NE) * 64;
  hptr[1][0] = hB; hptr[1][1] = hB + (size_t)NP * 64; hptr[1][2] = hB + (size_t)(NP + NE) * 64;
  ushort* gs[3] = {g, g + (size_t)NP * 64, g + (size_t)(NP + NE) * 64};

  // relations: 0 pp 1 fp 2 ep (dst P) | 3 pf 4 ef 5 ff (dst F) | 6 pe 7 fe (dst E)
  const int* ei[8] = {(const int*)d_in[6],  (const int*)d_in[7],
                      (const int*)d_in[8],  (const int*)d_in[9],
                      (const int*)d_in[10], (const int*)d_in[11],
                      (const int*)d_in[12], (const int*)d_in[13]};
  int ndst[8] = {NP, NP, NP, NF, NF, NF, NE, NE};
  int base[8];
  base[0] = 0;
  for (int r = 1; r < 8; ++r) base[r] = base[r - 1] + ndst[r - 1];

  EIPack ep;
  ep.e0 = ei[0]; ep.e1 = ei[1]; ep.e2 = ei[2]; ep.e3 = ei[3];
  ep.e4 = ei[4]; ep.e5 = ei[5]; ep.e6 = ei[6]; ep.e7 = ei[7];
  ep.b0 = base[0]; ep.b1 = base[1]; ep.b2 = base[2]; ep.b3 = base[3];
  ep.b4 = base[4]; ep.b5 = base[5]; ep.b6 = base[6]; ep.b7 = base[7];

  // ---- CSR build (edge indices shared by both layers) ----
  const int cblk = (Eg + 255) / 256;
  hipMemsetAsync(cur, 0, (size_t)NDSUM * 4, stream);
  for (int k = 0; k < COUNT_PASSES; ++k) {
    int c0 = (int)((size_t)NDSUM * k / COUNT_PASSES);
    int c1 = (int)((size_t)NDSUM * (k + 1) / COUNT_PASSES);
    count8_kernel<<<8 * cblk, 256, 0, stream>>>(ep, cur, Eg, cblk, c0, c1);
  }
  const int nb = (NDSUM + 1023) / 1024;
  scan1_kernel<<<nb, 256, 0, stream>>>(cur, part, NDSUM);
  scan2_kernel<<<1, 1024, 0, stream>>>(part, off, nb, NDSUM, 8 * Eg);
  scan3_kernel<<<nb, 256, 0, stream>>>(cur, part, off, cur, NDSUM);
  for (int k = 0; k < FILL_PASSES; ++k) {
    int c0 = (int)((size_t)NDSUM * k / FILL_PASSES);
    int c1 = (int)((size_t)NDSUM * (k + 1) / FILL_PASSES);
    fill8_kernel<<<8 * cblk, 256, 0, stream>>>(ep, cur, srcs, Eg, cblk, c0, c1);
  }

  // ---- weight prep ----
  prep_kernel<<<(25 * 4096 + 6 * 64 + 255) / 256, 256, 0, stream>>>(
      Wl, Wr, blp, (const float*)d_in[16], (const float*)d_in[20],
      (const float*)d_in[24], fw, bls);

  auto gblk = [](int n) { return ((n + 31) / 32 + 3) / 4; };
  auto launch_gemm = [&](GJob a, GJob b, GJob c, GJob d, int cnt) {
    GJobs js;
    js.j0 = a; js.j1 = b; js.j2 = c; js.j3 = d;
    int mx = gblk(a.n);
    mx = max(mx, gblk(b.n));
    if (cnt > 2) mx = max(mx, gblk(c.n));
    if (cnt > 3) mx = max(mx, gblk(d.n));
    gemm_multi_kernel<<<dim3(mx, cnt), 256, 0, stream>>>(js);
  };

  // ---- input MLPs (stage1 VALU -> staging, stage2 batched MFMA -> hA) ----
  mlp1_kernel<3><<<1024, 256, 0, stream>>>(point_x, (const float*)d_in[14],
      (const float*)d_in[15], gs[0], NP);
  mlp1_kernel<2><<<1024, 256, 0, stream>>>(edge_x, (const float*)d_in[18],
      (const float*)d_in[19], gs[1], NE);
  mlp1_kernel<16><<<1024, 256, 0, stream>>>(face_x, (const float*)d_in[22],
      (const float*)d_in[23], gs[2], NF);
  launch_gemm({gs[0], fw + 22 * 4096, (const float*)d_in[17], hptr[0][0], NP},
              {gs[1], fw + 23 * 4096, (const float*)d_in[21], hptr[0][1], NE},
              {gs[2], fw + 24 * 4096, (const float*)d_in[25], hptr[0][2], NF},
              {gs[2], fw + 24 * 4096, nullptr, hptr[0][2], 0}, 3);

  auto gfblk = [](int n) { return (n * 8 + 255) / 256; };

  // ---- 2 hetero-SAGE layers (read set cs, write set ns) ----
  int cs = 0;
  for (int i = 0; i < 2; ++i) {
    int ns = cs ^ 1;
    ushort* hp_ = hptr[cs][0];
    ushort* he_ = hptr[cs][1];
    ushort* hf_ = hptr[cs][2];
    // point phase: rels 0(src p),1(src f),2(src e) + t = hp@Wrs
    launch_gemm({hp_, fw + (size_t)(i * 8 + 0) * 4096, nullptr, gs[0], NP},
                {hf_, fw + (size_t)(i * 8 + 1) * 4096, nullptr, gs[1], NF},
                {he_, fw + (size_t)(i * 8 + 2) * 4096, nullptr, gs[2], NE},
                {hp_, fw + (size_t)(16 + i * 3 + 0) * 4096, nullptr, tb, NP}, 4);
    gf_kernel<<<gfblk(NP), 256, 0, stream>>>(gs[0], gs[1], gs[2], srcs, off,
        base[0], base[1], base[2], 3, tb, hp_, hptr[ns][0],
        bls + (i * 3 + 0) * 64, lng + (i * 3 + 0) * 64, lnb + (i * 3 + 0) * 64, NP);
    // face phase: rels 3(src p),4(src e),5(src f) + t = hf@Wrs
    launch_gemm({hp_, fw + (size_t)(i * 8 + 3) * 4096, nullptr, gs[0], NP},
                {he_, fw + (size_t)(i * 8 + 4) * 4096, nullptr, gs[1], NE},
                {hf_, fw + (size_t)(i * 8 + 5) * 4096, nullptr, gs[2], NF},
                {hf_, fw + (size_t)(16 + i * 3 + 2) * 4096, nullptr, tb, NF}, 4);
    gf_kernel<<<gfblk(NF), 256, 0, stream>>>(gs[0], gs[1], gs[2], srcs, off,
        base[3], base[4], base[5], 3, tb, hf_, hptr[ns][2],
        bls + (i * 3 + 2) * 64, lng + (i * 3 + 2) * 64, lnb + (i * 3 + 2) * 64, NF);
    // edge phase: rels 6(src p),7(src f) + t = he@Wrs
    launch_gemm({hp_, fw + (size_t)(i * 8 + 6) * 4096, nullptr, gs[0], NP},
                {hf_, fw + (size_t)(i * 8 + 7) * 4096, nullptr, gs[1], NF},
                {he_, fw + (size_t)(16 + i * 3 + 1) * 4096, nullptr, tb, NE},
                {he_, fw + (size_t)(16 + i * 3 + 1) * 4096, nullptr, tb, 0}, 3);
    gf_kernel<<<gfblk(NE), 256, 0, stream>>>(gs[0], gs[1], nullptr, srcs, off,
        base[6], base[7], 0, 2, tb, he_, hptr[ns][1],
        bls + (i * 3 + 1) * 64, lng + (i * 3 + 1) * 64, lnb + (i * 3 + 1) * 64, NE);
    cs = ns;
  }

  // ---- pool + scale ----
  float* out = (float*)d_out;
  hipMemsetAsync(out, 0, (size_t)out_size * sizeof(float), stream);
  PoolArgs pa;
  pa.h0 = hptr[cs][0]; pa.h1 = hptr[cs][1]; pa.h2 = hptr[cs][2];
  pa.b0 = bp; pa.b1 = be; pa.b2 = bf;
  pa.n0 = NP; pa.n1 = NE; pa.n2 = NF;
  pool_kernel<<<dim3(64 * POOL_SPLIT, 3), 64, 0, stream>>>(pa, out);
  pool_scale_kernel<<<(64 * 192 + 255) / 256, 256, 0, stream>>>(out, bp, be, bf, NP, NE, NF);
}